// Round 5
// baseline (1103.495 us; speedup 1.0000x reference)
//
#include <hip/hip_runtime.h>
#include <hip/hip_bf16.h>
#include <hip/hip_cooperative_groups.h>
#include <math.h>

namespace cg = cooperative_groups;

// ---------------------------------------------------------------------------
// DriverGeneGNN: 2-slice GCN (64->64->128) + BN + residual + MLP head.
// N=50000, E=1600000. fp32 accumulate, bf16 operands + bf16 intermediates.
// R17: ONE persistent cooperative kernel. R16 analysis: all own kernels
//      <40us; wall 353us vs ~230us (kernels+fill) -> ~120us of launch gaps
//      across 11 dispatches. All phases now grid-stride inside one
//      hipLaunchCooperativeKernel with 10 grid.sync()s (device-scope fences
//      handle cross-XCD visibility). __launch_bounds__(256,4): VGPR<=128,
//      LDS 34KB (union) -> 4 blocks/CU -> grid = 4*CU co-resident, 16
//      waves/CU for every phase (vs R15-fusion's 18% occupancy failure --
//      phases keep their own best inner structure, sync replaces launch).
// R16: un-fused gather (occupancy lesson); R14 pipelined gather;
// R13 LDS-swizzled epilogues.
// MFMA frag layouts (HW-verified): A[m=lane&15][k=(lane>>4)*8+j],
//     B[k][n=lane&15], C/D col=lane&15 row=(lane>>4)*4+reg.
// Conv biases cancel in BN -> skipped.
// ---------------------------------------------------------------------------

typedef short v8s __attribute__((ext_vector_type(8)));
typedef float f32x4 __attribute__((ext_vector_type(4)));

#define BSTRIDE 10240  // u32 slots per 256-col bucket segment (mean 8184)

__device__ __forceinline__ float sanf(float v) {
    if (v != v) return 0.f;
    if (isinf(v)) return v > 0.f ? 100.f : -100.f;
    return v;
}
__device__ __forceinline__ unsigned short bf16of(float v) {
    __hip_bfloat16 h = __float2bfloat16(v);
    return *(unsigned short*)&h;
}
__device__ __forceinline__ unsigned pack2(float lo, float hi) {
    return (unsigned)bf16of(lo) | ((unsigned)bf16of(hi) << 16);
}
__device__ __forceinline__ float uflo(unsigned u) { return __uint_as_float(u << 16); }
__device__ __forceinline__ float ufhi(unsigned u) { return __uint_as_float(u & 0xFFFF0000u); }

struct Params {
    const float* x;
    const int *ei0, *ei1;
    const float *w0_0, *w0_1, *w1_0, *w1_1, *r_0, *r_1, *fc1;
    const float *bn_g0, *bn_b0, *bn_g1, *bn_b1;
    const float *fc1_b, *fc2_w, *fc2_b;
    float* out;
    unsigned short* t0b;   // == Tb  (X1 overlay)
    unsigned short *Gb, *h1b, *comb, *xsb, *h1sb;
    float *dinv, *sums;
    unsigned* wpk;
    unsigned short* csr;
    int *rowptr, *bcnt;
    unsigned* binned;
    int n, E, NB, BPS;
};

union SMemU {
    struct { int cnt[512]; int base[512]; } c;                  // kC
    struct { int red[256]; int cnt[256]; int scn[256]; int cur[256]; } d;  // kD
    struct { unsigned short stb[64 * 128]; } g;                 // gemm C-stage
    struct { float st[64 * 128]; } a1;                          // apply1 C-stage
};

__device__ __forceinline__ void packone(const float* __restrict__ src, unsigned* __restrict__ dst,
                                        int L, int Khalf, int F) {
    int c = L / Khalf, kp = L - c * Khalf;
    dst[L] = pack2(src[(2 * kp) * F + c], src[(2 * kp + 1) * F + c]);
}

// --- gather core (R14/R16: 2-deep pipelined, predicated tail) ---------------
#define LOAD8(U, IDX)                                                       \
    do {                                                                    \
        _Pragma("unroll") for (int j = 0; j < 8; ++j) {                     \
            int r = __shfl((IDX), j, 8);                                    \
            (U)[j] = *(const uint4*)&mb[(size_t)r * 64 + l * 8];            \
        }                                                                   \
    } while (0)
#define ZPAD8(U, BB)                                                        \
    do {                                                                    \
        _Pragma("unroll") for (int j = 0; j < 8; ++j)                       \
            if ((BB) + j >= e) { (U)[j].x = 0; (U)[j].y = 0;                \
                                 (U)[j].z = 0; (U)[j].w = 0; }              \
    } while (0)
#define ACC8(U)                                                             \
    do {                                                                    \
        _Pragma("unroll") for (int j = 0; j < 8; ++j) {                     \
            a0 += uflo((U)[j].x); a1 += ufhi((U)[j].x);                     \
            a2 += uflo((U)[j].y); a3 += ufhi((U)[j].y);                     \
            a4 += uflo((U)[j].z); a5 += ufhi((U)[j].z);                     \
            a6 += uflo((U)[j].w); a7 += ufhi((U)[j].w);                     \
        }                                                                   \
    } while (0)

__device__ __forceinline__ void gather_node(const int* __restrict__ rowptr,
                                            const unsigned short* __restrict__ csr,
                                            const unsigned short* __restrict__ mb,
                                            const float* __restrict__ dinv,
                                            int node, int l,
                                            unsigned short* __restrict__ outrow) {
    int s = rowptr[node], e = rowptr[node + 1];
    float a0 = 0.f, a1 = 0.f, a2 = 0.f, a3 = 0.f, a4 = 0.f, a5 = 0.f, a6 = 0.f, a7 = 0.f;
    uint4 uA[8], uB[8];
    int b = s;
    if (b + 8 <= e) {
        int ia = csr[b + l];
        LOAD8(uA, ia);
        int bB = b + 8;
        int ib = (bB + l < e) ? (int)csr[bB + l] : 0;
        while (true) {
            bool hasB = (bB < e);
            if (hasB) {
                LOAD8(uB, ib);
                if (bB + 8 > e) ZPAD8(uB, bB);
            }
            int bA2 = bB + 8;
            if (bA2 < e) ia = (bA2 + l < e) ? (int)csr[bA2 + l] : 0;
            ACC8(uA);
            if (!hasB) break;
            bool hasA2 = (bA2 < e);
            if (hasA2) {
                LOAD8(uA, ia);
                if (bA2 + 8 > e) ZPAD8(uA, bA2);
            }
            int bB2 = bA2 + 8;
            if (bB2 < e) ib = (bB2 + l < e) ? (int)csr[bB2 + l] : 0;
            ACC8(uB);
            if (!hasA2) break;
            bB = bB2;
        }
    } else if (b < e) {
        int ia = (b + l < e) ? (int)csr[b + l] : 0;
        LOAD8(uA, ia);
        ZPAD8(uA, b);
        ACC8(uA);
    }
    float d = dinv[node];
    uint4 o;
    o.x = pack2(a0 * d, a1 * d);
    o.y = pack2(a2 * d, a3 * d);
    o.z = pack2(a4 * d, a5 * d);
    o.w = pack2(a6 * d, a7 * d);
    *(uint4*)&outrow[l * 8] = o;
}

// --- gemm tiles (grid-stride; swizzled LDS C-stage; fused BN stats) ---------
template <int F>
__device__ __forceinline__ void gemm_tiles(const unsigned short* __restrict__ Ab,
                                           const unsigned* __restrict__ WT0,
                                           const unsigned* __restrict__ WT1,
                                           unsigned short* __restrict__ Cb,
                                           float* __restrict__ sums,
                                           int roff, int n, int BPS,
                                           unsigned short* stb, float* ls) {
    constexpr int NC = F / 16;
    const int t = threadIdx.x;
    const int G = gridDim.x;
    for (int tile = blockIdx.x; tile < 2 * BPS; tile += G) {
        int slice = tile >= BPS;
        int sb = tile - slice * BPS;
        const unsigned* WT = slice ? WT1 : WT0;
        int row0 = slice * n + sb * 64;
        int rows = min(64, n - sb * 64);
        for (int i = t; i < 2 * F; i += 256) ls[i] = 0.f;
        int w = t >> 6, lane = t & 63, q = lane >> 4, ln = lane & 15;
        const unsigned* A32 = (const unsigned*)Ab;
        size_t arow = (size_t)(row0 + 16 * w + ln) * 32;
        v8s af0 = *(const v8s*)&A32[arow + q * 4];
        v8s af1 = *(const v8s*)&A32[arow + 16 + q * 4];
        f32x4 acc[NC];
#pragma unroll
        for (int ct = 0; ct < NC; ++ct) acc[ct] = {0.f, 0.f, 0.f, 0.f};
#pragma unroll
        for (int ct = 0; ct < NC; ++ct) {
            v8s b0 = *(const v8s*)&WT[(ct * 16 + ln) * 32 + q * 4];
            v8s b1 = *(const v8s*)&WT[(ct * 16 + ln) * 32 + 16 + q * 4];
            acc[ct] = __builtin_amdgcn_mfma_f32_16x16x32_bf16(af0, b0, acc[ct], 0, 0, 0);
            acc[ct] = __builtin_amdgcn_mfma_f32_16x16x32_bf16(af1, b1, acc[ct], 0, 0, 0);
        }
        __syncthreads();  // ls zero visible; stb free from prev tile
#pragma unroll
        for (int ct = 0; ct < NC; ++ct) {
            float s1 = 0.f, s2 = 0.f;
            int cc = ct * 16 + ln;
#pragma unroll
            for (int i = 0; i < 4; ++i) {
                int r = 16 * w + q * 4 + i;
                stb[r * F + (cc ^ ((r & 7) << 3))] = bf16of(acc[ct][i]);
                if (r < rows) {
                    float v = acc[ct][i];
                    s1 += v;
                    s2 += v * v;
                }
            }
            s1 += __shfl_xor(s1, 16); s1 += __shfl_xor(s1, 32);
            s2 += __shfl_xor(s2, 16); s2 += __shfl_xor(s2, 32);
            if (q == 0) {
                atomicAdd(&ls[cc], s1);
                atomicAdd(&ls[F + cc], s2);
            }
        }
        __syncthreads();  // stb + ls complete
        {
            constexpr int CPT = F / 4;
            int rr = t >> 2, sg = t & 3;
            if (rr < rows) {
                int swz = (rr & 7) << 3;
                int cb = sg * CPT;
                uint4* dst = (uint4*)(Cb + (size_t)(row0 + rr) * F + cb);
#pragma unroll
                for (int jj = 0; jj < CPT / 8; ++jj)
                    dst[jj] = *(const uint4*)&stb[rr * F + ((cb + jj * 8) ^ swz)];
            }
        }
        if (t < F) {
            float* dst = sums + (blockIdx.x & 7) * 1024 + roff + slice * 2 * F;
            unsafeAtomicAdd(&dst[t], ls[t]);
            unsafeAtomicAdd(&dst[F + t], ls[F + t]);
        }
        __syncthreads();  // protect ls/stb reuse next tile
    }
}

// --- THE persistent kernel ---------------------------------------------------
__global__ __launch_bounds__(256, 4) void fused_all(Params p) {
    cg::grid_group grid = cg::this_grid();
    __shared__ SMemU sm;
    __shared__ float scl[512];
    const int t = threadIdx.x;
    const int bid = blockIdx.x;
    const int G = gridDim.x;
    const int n = p.n, E = p.E;
    const int n2 = 2 * n, E2 = 2 * E, n64 = n * 64;
    const int NB = p.NB, BPS = p.BPS;
    unsigned* w0T0 = p.wpk + 0,    *w0T1 = p.wpk + 2048;
    unsigned* w1T0 = p.wpk + 4096, *w1T1 = p.wpk + 8192;
    unsigned* rT0  = p.wpk + 12288,*rT1  = p.wpk + 16384;
    unsigned* fT   = p.wpk + 20480;

    // ---- phase 0: weight pack + zero bcnt/sums ----
    for (int gid = bid * 256 + t; gid < 36864; gid += G * 256) {
        if (gid < 512) p.bcnt[gid] = 0;
        if (gid < 8192) p.sums[gid] = 0.f;
        if (gid < 2048)       packone(p.w0_0, p.wpk + 0,     gid - 0,     32, 64);
        else if (gid < 4096)  packone(p.w0_1, p.wpk + 2048,  gid - 2048,  32, 64);
        else if (gid < 8192)  packone(p.w1_0, p.wpk + 4096,  gid - 4096,  32, 128);
        else if (gid < 12288) packone(p.w1_1, p.wpk + 8192,  gid - 8192,  32, 128);
        else if (gid < 16384) packone(p.r_0,  p.wpk + 12288, gid - 12288, 32, 128);
        else if (gid < 20480) packone(p.r_1,  p.wpk + 16384, gid - 16384, 32, 128);
        else                  packone(p.fc1,  p.wpk + 20480, gid - 20480, 128, 128);
    }
    grid.sync();

    // ---- phase 1: bin edges (chunks of 4096 = 256 thr x 16) ----
    {
        int nch = (E2 + 4095) >> 12;
        for (int ch = bid; ch < nch; ch += G) {
            sm.c.cnt[t] = 0; sm.c.cnt[t + 256] = 0;
            __syncthreads();
            unsigned pk[16]; int bk[16];
            int e0 = ch * 4096;
#pragma unroll
            for (int j = 0; j < 16; ++j) {
                int ge = e0 + t + j * 256;
                bk[j] = -1;
                if (ge < E2) {
                    int slice = ge >= E;
                    const int* ei = slice ? p.ei1 : p.ei0;
                    int e = ge - slice * E;
                    int col = ei[E + e], row = ei[e];
                    int gcol = slice * n + col;
                    bk[j] = gcol >> 8;
                    pk[j] = (unsigned)row | (((unsigned)gcol & 255u) << 16);
                    atomicAdd(&sm.c.cnt[bk[j]], 1);
                }
            }
            __syncthreads();
            for (int i = t; i < 512; i += 256) {
                int c = sm.c.cnt[i];
                sm.c.base[i] = c ? atomicAdd(&p.bcnt[i], c) : 0;
            }
            __syncthreads();
            sm.c.cnt[t] = 0; sm.c.cnt[t + 256] = 0;
            __syncthreads();
#pragma unroll
            for (int j = 0; j < 16; ++j) {
                if (bk[j] >= 0) {
                    int loc = atomicAdd(&sm.c.cnt[bk[j]], 1);
                    int off = sm.c.base[bk[j]] + loc;
                    if (off < BSTRIDE) p.binned[(size_t)bk[j] * BSTRIDE + off] = pk[j];
                }
            }
            __syncthreads();
        }
    }
    grid.sync();

    // ---- phase 2: build CSR per bucket ----
    for (int b = bid; b < NB; b += G) {
        int partial = 0;
        for (int i = t; i < b; i += 256) partial += p.bcnt[i];
        sm.d.red[t] = partial;
        __syncthreads();
        for (int off = 128; off > 0; off >>= 1) {
            if (t < off) sm.d.red[t] += sm.d.red[t + off];
            __syncthreads();
        }
        int s = sm.d.red[0];
        int e = s + p.bcnt[b];
        int m = e - s;
        const unsigned* seg = p.binned + (size_t)b * BSTRIDE;
        sm.d.cnt[t] = 0;
        __syncthreads();
        for (int i = t; i < m; i += 256) atomicAdd(&sm.d.cnt[(seg[i] >> 16) & 255], 1);
        __syncthreads();
        int v = sm.d.cnt[t];
        sm.d.scn[t] = v;
        __syncthreads();
        for (int off = 1; off < 256; off <<= 1) {
            int u = (t >= off) ? sm.d.scn[t - off] : 0;
            __syncthreads();
            sm.d.scn[t] += u;
            __syncthreads();
        }
        {
            int excl = sm.d.scn[t] - v;
            int gcol = b * 256 + t;
            if (gcol < n2) {
                p.rowptr[gcol] = s + excl;
                p.dinv[gcol] = v > 0 ? rsqrtf((float)v) : 0.f;
            }
            sm.d.cur[t] = excl;
        }
        __syncthreads();
        for (int i = t; i < m; i += 256) {
            unsigned pkv = seg[i];
            int cl = (pkv >> 16) & 255;
            int pos = s + atomicAdd(&sm.d.cur[cl], 1);
            p.csr[pos] = (unsigned short)(pkv & 0xFFFFu);
        }
        if (b == NB - 1 && t == 0) p.rowptr[n2] = e;
        __syncthreads();
    }
    grid.sync();

    // ---- phase 3: prescale x*dinv -> xsb (both slices) ----
    for (int i8 = (bid * 256 + t) * 8; i8 < n64; i8 += G * 256 * 8) {
        int row = i8 >> 6;
        float4 v0 = *(const float4*)&p.x[i8];
        float4 v1 = *(const float4*)&p.x[i8 + 4];
        float d0 = p.dinv[row], d1 = p.dinv[n + row];
        uint4 o0, o1;
        o0.x = pack2(v0.x * d0, v0.y * d0); o0.y = pack2(v0.z * d0, v0.w * d0);
        o0.z = pack2(v1.x * d0, v1.y * d0); o0.w = pack2(v1.z * d0, v1.w * d0);
        o1.x = pack2(v0.x * d1, v0.y * d1); o1.y = pack2(v0.z * d1, v0.w * d1);
        o1.z = pack2(v1.x * d1, v1.y * d1); o1.w = pack2(v1.z * d1, v1.w * d1);
        *(uint4*)&p.xsb[i8] = o0;
        *(uint4*)&p.xsb[n64 + i8] = o1;
    }
    grid.sync();

    // ---- phase 4: gather layer 0 ----
    {
        int l = t & 7;
        for (int base = bid * 32; base < n2; base += G * 32) {
            int node = base + (t >> 3);
            if (node < n2) {
                const unsigned short* mb = p.xsb + (size_t)((node >= n) ? n : 0) * 64;
                gather_node(p.rowptr, p.csr, mb, p.dinv, node, l, p.Gb + (size_t)node * 64);
            }
        }
    }
    grid.sync();

    // ---- phase 5: gemm64 (+BN stats, roff 512) ----
    gemm_tiles<64>(p.Gb, w0T0, w0T1, p.t0b, p.sums, 512, n, BPS, sm.g.stb, scl);
    grid.sync();

    // ---- phase 6: BN finalize (64) + apply0 ----
    if (t < 128) {
        int slice = t >> 6, f = t & 63;
        float s1 = 0.f, s2 = 0.f;
#pragma unroll
        for (int r = 0; r < 8; ++r) {
            const float* src = p.sums + r * 1024 + 512 + slice * 128;
            s1 += src[f];
            s2 += src[64 + f];
        }
        float inv_n = 1.0f / (float)n;
        float mu = s1 * inv_n;
        float var = fmaxf(s2 * inv_n - mu * mu, 0.f);
        float scale = p.bn_g0[f] * rsqrtf(var + 1e-5f);
        scl[slice * 128 + f] = scale;
        scl[slice * 128 + 64 + f] = p.bn_b0[f] - mu * scale;
    }
    __syncthreads();
    for (int i8 = (bid * 256 + t) * 8; i8 < 2 * n64; i8 += G * 256 * 8) {
        int slice = i8 >= n64;
        int f0 = i8 & 63;
        const float* scp = scl + slice * 128;
        uint4 tv = *(const uint4*)&p.t0b[i8];
        const float* xp = p.x + (i8 - slice * n64);
        float4 x0 = *(const float4*)xp;
        float4 x1 = *(const float4*)(xp + 4);
        float4 s0 = *(const float4*)&scp[f0];
        float4 s1 = *(const float4*)&scp[f0 + 4];
        float4 g0 = *(const float4*)&scp[64 + f0];
        float4 g1 = *(const float4*)&scp[64 + f0 + 4];
        float d = p.dinv[i8 >> 6];
        float tvv[8] = {uflo(tv.x), ufhi(tv.x), uflo(tv.y), ufhi(tv.y),
                        uflo(tv.z), ufhi(tv.z), uflo(tv.w), ufhi(tv.w)};
        float sa[8] = {s0.x, s0.y, s0.z, s0.w, s1.x, s1.y, s1.z, s1.w};
        float sh[8] = {g0.x, g0.y, g0.z, g0.w, g1.x, g1.y, g1.z, g1.w};
        float xv[8] = {x0.x, x0.y, x0.z, x0.w, x1.x, x1.y, x1.z, x1.w};
        unsigned po[4], ps[4];
#pragma unroll
        for (int j = 0; j < 4; ++j) {
            float a = sanf(fmaxf(fmaf(tvv[2 * j], sa[2 * j], sh[2 * j]), 0.f) + xv[2 * j]);
            float b2 = sanf(fmaxf(fmaf(tvv[2 * j + 1], sa[2 * j + 1], sh[2 * j + 1]), 0.f) + xv[2 * j + 1]);
            po[j] = pack2(a, b2);
            ps[j] = pack2(a * d, b2 * d);
        }
        *(uint4*)&p.h1b[i8] = *(uint4*)po;
        *(uint4*)&p.h1sb[i8] = *(uint4*)ps;
    }
    grid.sync();

    // ---- phase 7: gather layer 1 ----
    {
        int l = t & 7;
        for (int base = bid * 32; base < n2; base += G * 32) {
            int node = base + (t >> 3);
            if (node < n2) {
                const unsigned short* mb = p.h1sb + (size_t)((node >= n) ? n : 0) * 64;
                gather_node(p.rowptr, p.csr, mb, p.dinv, node, l, p.Gb + (size_t)node * 64);
            }
        }
    }
    grid.sync();

    // ---- phase 8: gemm128 (+BN stats, roff 0) ----
    gemm_tiles<128>(p.Gb, w1T0, w1T1, p.t0b /*Tb overlay*/, p.sums, 0, n, BPS, sm.g.stb, scl);
    grid.sync();

    // ---- phase 9: BN finalize (128) + apply1 ----
    {
        int slice = t >> 7, f = t & 127;
        float s1 = 0.f, s2 = 0.f;
#pragma unroll
        for (int r = 0; r < 8; ++r) {
            const float* src = p.sums + r * 1024 + slice * 256;
            s1 += src[f];
            s2 += src[128 + f];
        }
        float inv_n = 1.0f / (float)n;
        float mu = s1 * inv_n;
        float var = fmaxf(s2 * inv_n - mu * mu, 0.f);
        const float* g = p.bn_g1;
        const float* be = p.bn_b1;
        float scale = g[f] * rsqrtf(var + 1e-5f);
        scl[slice * 256 + f] = scale;
        scl[slice * 256 + 128 + f] = be[f] - mu * scale;
    }
    __syncthreads();
    for (int tile = bid; tile < 2 * BPS; tile += G) {
        int slice = tile >= BPS;
        int sb = tile - slice * BPS;
        const unsigned* WT = slice ? rT1 : rT0;
        int row0 = slice * n + sb * 64;
        int rows = min(64, n - sb * 64);
        int w = t >> 6, lane = t & 63, q = lane >> 4, ln = lane & 15;
        const unsigned* A32 = (const unsigned*)p.h1b;
        size_t arow = (size_t)(row0 + 16 * w + ln) * 32;
        v8s af0 = *(const v8s*)&A32[arow + q * 4];
        v8s af1 = *(const v8s*)&A32[arow + 16 + q * 4];
        f32x4 acc[8];
#pragma unroll
        for (int ct = 0; ct < 8; ++ct) acc[ct] = {0.f, 0.f, 0.f, 0.f};
#pragma unroll
        for (int ct = 0; ct < 8; ++ct) {
            v8s b0 = *(const v8s*)&WT[(ct * 16 + ln) * 32 + q * 4];
            v8s b1 = *(const v8s*)&WT[(ct * 16 + ln) * 32 + 16 + q * 4];
            acc[ct] = __builtin_amdgcn_mfma_f32_16x16x32_bf16(af0, b0, acc[ct], 0, 0, 0);
            acc[ct] = __builtin_amdgcn_mfma_f32_16x16x32_bf16(af1, b1, acc[ct], 0, 0, 0);
        }
#pragma unroll
        for (int ct = 0; ct < 8; ++ct) {
            int cc = ct * 16 + ln;
#pragma unroll
            for (int i = 0; i < 4; ++i) {
                int r = 16 * w + q * 4 + i;
                sm.a1.st[r * 128 + (cc ^ ((r & 7) << 2))] = acc[ct][i];
            }
        }
        __syncthreads();
        int rr = t >> 2, sg = t & 3;
        if (rr < rows) {
            int swz = (rr & 7) << 2;
            int rg = row0 + rr;
            const uint4* tbp = (const uint4*)(p.t0b + (size_t)rg * 128 + sg * 32);
            const float* scb = scl + slice * 256 + sg * 32;
            uint4* outp = (uint4*)(p.comb + (size_t)(rg - slice * n) * 256 + slice * 128 + sg * 32);
#pragma unroll
            for (int jj = 0; jj < 4; ++jj) {
                uint4 tv = tbp[jj];
                int base = sg * 32 + jj * 8;
                float4 a0 = *(const float4*)&sm.a1.st[rr * 128 + (base ^ swz)];
                float4 a1 = *(const float4*)&sm.a1.st[rr * 128 + ((base + 4) ^ swz)];
                float4 s0 = *(const float4*)&scb[jj * 8];
                float4 s1 = *(const float4*)&scb[jj * 8 + 4];
                float4 h0 = *(const float4*)&scb[128 + jj * 8];
                float4 h1v = *(const float4*)&scb[128 + jj * 8 + 4];
                float o0 = sanf(fmaf(uflo(tv.x), s0.x, h0.x) + a0.x);
                float o1 = sanf(fmaf(ufhi(tv.x), s0.y, h0.y) + a0.y);
                float o2 = sanf(fmaf(uflo(tv.y), s0.z, h0.z) + a0.z);
                float o3 = sanf(fmaf(ufhi(tv.y), s0.w, h0.w) + a0.w);
                float o4 = sanf(fmaf(uflo(tv.z), s1.x, h1v.x) + a1.x);
                float o5 = sanf(fmaf(ufhi(tv.z), s1.y, h1v.y) + a1.y);
                float o6 = sanf(fmaf(uflo(tv.w), s1.z, h1v.z) + a1.z);
                float o7 = sanf(fmaf(ufhi(tv.w), s1.w, h1v.w) + a1.w);
                uint4 ov;
                ov.x = pack2(o0, o1);
                ov.y = pack2(o2, o3);
                ov.z = pack2(o4, o5);
                ov.w = pack2(o6, o7);
                outp[jj] = ov;
            }
        }
        __syncthreads();
    }
    grid.sync();

    // ---- phase 10: head (fc1 + relu + fc2 + softmax) ----
    for (int tile = bid; tile < BPS; tile += G) {
        int row0 = tile * 64;
        int rows = min(64, n - row0);
        int w = t >> 6, lane = t & 63, q = lane >> 4, ln = lane & 15;
        const unsigned* A32 = (const unsigned*)p.comb;
        size_t arow = (size_t)(row0 + 16 * w + ln) * 128;
        f32x4 acc[8];
#pragma unroll
        for (int ct = 0; ct < 8; ++ct) acc[ct] = {0.f, 0.f, 0.f, 0.f};
#pragma unroll
        for (int kt = 0; kt < 4; ++kt) {
            v8s af0 = *(const v8s*)&A32[arow + kt * 32 + q * 4];
            v8s af1 = *(const v8s*)&A32[arow + kt * 32 + 16 + q * 4];
#pragma unroll
            for (int ct = 0; ct < 8; ++ct) {
                v8s b0 = *(const v8s*)&fT[(ct * 16 + ln) * 128 + kt * 32 + q * 4];
                v8s b1 = *(const v8s*)&fT[(ct * 16 + ln) * 128 + kt * 32 + 16 + q * 4];
                acc[ct] = __builtin_amdgcn_mfma_f32_16x16x32_bf16(af0, b0, acc[ct], 0, 0, 0);
                acc[ct] = __builtin_amdgcn_mfma_f32_16x16x32_bf16(af1, b1, acc[ct], 0, 0, 0);
            }
        }
        float p0[4] = {0.f, 0.f, 0.f, 0.f}, p1[4] = {0.f, 0.f, 0.f, 0.f};
#pragma unroll
        for (int ct = 0; ct < 8; ++ct) {
            int c = ct * 16 + ln;
            float bi = p.fc1_b[c];
            float w20 = p.fc2_w[c * 2], w21 = p.fc2_w[c * 2 + 1];
#pragma unroll
            for (int i = 0; i < 4; ++i) {
                float h = fmaxf(acc[ct][i] + bi, 0.f);
                p0[i] = fmaf(h, w20, p0[i]);
                p1[i] = fmaf(h, w21, p1[i]);
            }
        }
#pragma unroll
        for (int i = 0; i < 4; ++i) {
#pragma unroll
            for (int msk = 1; msk < 16; msk <<= 1) {
                p0[i] += __shfl_xor(p0[i], msk);
                p1[i] += __shfl_xor(p1[i], msk);
            }
        }
        if (ln == 0) {
            float bb0 = p.fc2_b[0], bb1 = p.fc2_b[1];
#pragma unroll
            for (int i = 0; i < 4; ++i) {
                int r = 16 * w + q * 4 + i;
                if (r >= rows) continue;
                int R = row0 + r;
                float l0 = p0[i] + bb0, l1 = p1[i] + bb1;
                float mx = fmaxf(l0, l1);
                float e0 = expf(l0 - mx), e1 = expf(l1 - mx);
                float inv = 1.0f / (e0 + e1);
                p.out[(size_t)R * 2] = l0;
                p.out[(size_t)R * 2 + 1] = l1;
                p.out[(size_t)2 * n + R * 2] = e0 * inv;
                p.out[(size_t)2 * n + R * 2 + 1] = e1 * inv;
            }
        }
    }
}

static inline int cdiv(int a, int b) { return (a + b - 1) / b; }

extern "C" void kernel_launch(void* const* d_in, const int* in_sizes, int n_in,
                              void* d_out, int out_size, void* d_ws, size_t ws_size,
                              hipStream_t stream) {
    Params hp;
    hp.x     = (const float*)d_in[0];
    hp.ei0   = (const int*)d_in[1];
    hp.ei1   = (const int*)d_in[2];
    hp.w0_0  = (const float*)d_in[3];
    hp.w1_0  = (const float*)d_in[5];
    hp.r_0   = (const float*)d_in[7];
    hp.w0_1  = (const float*)d_in[8];
    hp.w1_1  = (const float*)d_in[10];
    hp.r_1   = (const float*)d_in[12];
    hp.bn_g0 = (const float*)d_in[13];
    hp.bn_b0 = (const float*)d_in[14];
    hp.bn_g1 = (const float*)d_in[15];
    hp.bn_b1 = (const float*)d_in[16];
    hp.fc1   = (const float*)d_in[17];
    hp.fc1_b = (const float*)d_in[18];
    hp.fc2_w = (const float*)d_in[19];
    hp.fc2_b = (const float*)d_in[20];
    hp.out   = (float*)d_out;

    int n = in_sizes[0] / 64;   // 50000
    int E = in_sizes[1] / 2;    // 1600000
    int n2 = 2 * n, E2 = 2 * E;
    hp.n = n; hp.E = E;
    hp.NB = cdiv(n2, 256);      // 391
    hp.BPS = cdiv(n, 64);       // 782

    float* X1 = (float*)d_ws;                       // t0b/Tb region
    float* S  = X1 + (size_t)n2 * 64;               // h1sb region
    unsigned short* Gb   = (unsigned short*)(S + (size_t)n2 * 64);
    unsigned short* h1b  = Gb + (size_t)n2 * 64;
    unsigned short* comb = h1b + (size_t)n2 * 64;   // binned overlay
    unsigned short* xsb  = comb + (size_t)n * 256;
    float* dinv = (float*)(xsb + (size_t)n * 128);
    float* sums = dinv + n2;                        // [8][1024]
    float* scsh = sums + 8192;                      // (layout spacer)
    unsigned* wpk = (unsigned*)(scsh + 512);        // [36864]
    unsigned short* csr = (unsigned short*)(wpk + 36864);
    int* rowptr = (int*)(csr + (size_t)E2);
    int* bcnt   = rowptr + (n2 + 1);

    hp.t0b = (unsigned short*)X1;
    hp.Gb = Gb; hp.h1b = h1b; hp.comb = comb; hp.xsb = xsb;
    hp.h1sb = (unsigned short*)S;
    hp.dinv = dinv; hp.sums = sums; hp.wpk = wpk;
    hp.csr = csr; hp.rowptr = rowptr; hp.bcnt = bcnt;
    hp.binned = (unsigned*)comb;

    static int grid = 0;
    if (grid == 0) {
        int maxB = 0;
        hipError_t err = hipOccupancyMaxActiveBlocksPerMultiprocessor(
            &maxB, reinterpret_cast<const void*>(&fused_all), 256, 0);
        if (err != hipSuccess || maxB < 1) maxB = 2;
        int cu = 256;
        hipDeviceProp_t prop;
        int dev = 0;
        if (hipGetDevice(&dev) == hipSuccess &&
            hipGetDeviceProperties(&prop, dev) == hipSuccess)
            cu = prop.multiProcessorCount;
        grid = maxB * cu;
        if (grid > 2048) grid = 2048;
    }

    void* args[] = {(void*)&hp};
    hipLaunchCooperativeKernel(reinterpret_cast<const void*>(&fused_all),
                               dim3(grid), dim3(256), args, 0, stream);
}

// Round 6
// 347.228 us; speedup vs baseline: 3.1780x; 3.1780x over previous
//
#include <hip/hip_runtime.h>
#include <hip/hip_bf16.h>
#include <math.h>

// ---------------------------------------------------------------------------
// DriverGeneGNN: 2-slice GCN (64->64->128) + BN + residual + MLP head.
// N=50000, E=1600000. fp32 accumulate, bf16 operands + bf16 intermediates.
// R18: revert R17 coop mega-kernel (grid.sync on 8 XCDs = per-sync L2
//      flush + refetch: FETCH 115->324MB, all pipes idle, 1570us. LESSON:
//      kernel boundary IS the cheap grid barrier on MI355X). Back to R16
//      (353us) minus two boundaries: (a) prescale folded into kD_build tail
//      (bucket block owns its gcols' dinv in LDS); (b) apply1+head fused with
//      comb in LDS (XOR-swizzled 64x256 bf16, both slices staged, head reads
//      A-frags from LDS) -- kills comb's 2x25.6MB global round-trip. 9
//      dispatches.
// R16: un-fused gather (occupancy lesson); R14 pipelined gather;
// R13 LDS-swizzled epilogues.
// MFMA frag layouts (HW-verified): A[m=lane&15][k=(lane>>4)*8+j],
//     B[k][n=lane&15], C/D col=lane&15 row=(lane>>4)*4+reg.
// Conv biases cancel in BN -> skipped.
// ---------------------------------------------------------------------------

typedef short v8s __attribute__((ext_vector_type(8)));
typedef float f32x4 __attribute__((ext_vector_type(4)));

#define BSTRIDE 10240  // u32 slots per 256-col bucket segment (mean 8184)

__device__ __forceinline__ float sanf(float v) {
    if (v != v) return 0.f;
    if (isinf(v)) return v > 0.f ? 100.f : -100.f;
    return v;
}

__device__ __forceinline__ unsigned short bf16of(float v) {
    __hip_bfloat16 h = __float2bfloat16(v);
    return *(unsigned short*)&h;
}
__device__ __forceinline__ unsigned pack2(float lo, float hi) {
    return (unsigned)bf16of(lo) | ((unsigned)bf16of(hi) << 16);
}
__device__ __forceinline__ float uflo(unsigned u) { return __uint_as_float(u << 16); }
__device__ __forceinline__ float ufhi(unsigned u) { return __uint_as_float(u & 0xFFFF0000u); }

// --- prep: pack weights as W^T bf16-pairs + zero bcnt/sums ------------------
__device__ __forceinline__ void packone(const float* __restrict__ src, unsigned* __restrict__ dst,
                                        int L, int Khalf, int F) {
    int c = L / Khalf, kp = L - c * Khalf;
    dst[L] = pack2(src[(2 * kp) * F + c], src[(2 * kp + 1) * F + c]);
}

__global__ __launch_bounds__(256) void prep_kernel(const float* __restrict__ w0_0,
                                                   const float* __restrict__ w0_1,
                                                   const float* __restrict__ w1_0,
                                                   const float* __restrict__ w1_1,
                                                   const float* __restrict__ r_0,
                                                   const float* __restrict__ r_1,
                                                   const float* __restrict__ fc1,
                                                   unsigned* __restrict__ wpk,
                                                   int* __restrict__ bcnt,
                                                   float* __restrict__ sums) {
    int gid = blockIdx.x * 256 + threadIdx.x;
    if (gid < 512) bcnt[gid] = 0;
    if (gid < 8192) sums[gid] = 0.f;
    if (gid < 2048)       packone(w0_0, wpk + 0,     gid - 0,     32, 64);
    else if (gid < 4096)  packone(w0_1, wpk + 2048,  gid - 2048,  32, 64);
    else if (gid < 8192)  packone(w1_0, wpk + 4096,  gid - 4096,  32, 128);
    else if (gid < 12288) packone(w1_1, wpk + 8192,  gid - 8192,  32, 128);
    else if (gid < 16384) packone(r_0,  wpk + 12288, gid - 12288, 32, 128);
    else if (gid < 20480) packone(r_1,  wpk + 16384, gid - 16384, 32, 128);
    else if (gid < 36864) packone(fc1,  wpk + 20480, gid - 20480, 128, 128);
}

// --- CSR build --------------------------------------------------------------

__global__ __launch_bounds__(512) void kC_bin(const int* __restrict__ ei0,
                                              const int* __restrict__ ei1,
                                              int* __restrict__ bcnt,
                                              unsigned* __restrict__ binned,
                                              int E, int n) {
    __shared__ int cnt[512];
    __shared__ int base[512];
    int t = threadIdx.x;
    cnt[t] = 0;
    int E2 = 2 * E;
    int e0 = blockIdx.x * 8192;
    unsigned pk[16];
    int bk[16];
    __syncthreads();
#pragma unroll
    for (int j = 0; j < 16; ++j) {
        int ge = e0 + t + j * 512;
        bk[j] = -1;
        if (ge < E2) {
            int slice = ge >= E;
            const int* ei = slice ? ei1 : ei0;
            int e = ge - slice * E;
            int col = ei[E + e], row = ei[e];
            int gcol = slice * n + col;
            bk[j] = gcol >> 8;
            pk[j] = (unsigned)row | (((unsigned)gcol & 255u) << 16);
            atomicAdd(&cnt[bk[j]], 1);
        }
    }
    __syncthreads();
    {
        int c = cnt[t];
        base[t] = c ? atomicAdd(&bcnt[t], c) : 0;
    }
    __syncthreads();
    cnt[t] = 0;
    __syncthreads();
#pragma unroll
    for (int j = 0; j < 16; ++j) {
        if (bk[j] >= 0) {
            int loc = atomicAdd(&cnt[bk[j]], 1);
            int off = base[bk[j]] + loc;
            if (off < BSTRIDE) binned[(size_t)bk[j] * BSTRIDE + off] = pk[j];
        }
    }
}

// one block (512 thr) per 256-col bucket; per-block scan of bcnt (kB fused);
// prescale tail fused: this block owns dinv for its gcols -> write xsb rows.
__global__ __launch_bounds__(512) void kD_build(const unsigned* __restrict__ binned,
                                                const int* __restrict__ bcnt,
                                                const float* __restrict__ x,
                                                int* __restrict__ rowptr,
                                                float* __restrict__ dinv,
                                                unsigned short* __restrict__ csr,
                                                unsigned short* __restrict__ xsb,
                                                int n2, int NB) {
    __shared__ int pref[512];
    __shared__ int cnt[256];
    __shared__ int scn[256];
    __shared__ int cur[256];
    __shared__ float ds[256];
    int b = blockIdx.x, t = threadIdx.x;
    int n = n2 >> 1, n64 = n * 64;
    // inclusive scan of bcnt[0..NB) in LDS (NB <= 512)
    pref[t] = (t < NB) ? bcnt[t] : 0;
    __syncthreads();
    for (int off = 1; off < 512; off <<= 1) {
        int u = (t >= off) ? pref[t - off] : 0;
        __syncthreads();
        pref[t] += u;
        __syncthreads();
    }
    int s = (b > 0) ? pref[b - 1] : 0;
    int e = pref[b];
    int m = e - s;
    const unsigned* seg = binned + (size_t)b * BSTRIDE;
    if (t < 256) cnt[t] = 0;
    __syncthreads();
    for (int i = t; i < m; i += 512) atomicAdd(&cnt[(seg[i] >> 16) & 255], 1);
    __syncthreads();
    int v = (t < 256) ? cnt[t] : 0;
    if (t < 256) scn[t] = v;
    __syncthreads();
    for (int off = 1; off < 256; off <<= 1) {
        int u = (t < 256 && t >= off) ? scn[t - off] : 0;
        __syncthreads();
        if (t < 256) scn[t] += u;
        __syncthreads();
    }
    if (t < 256) {
        int excl = scn[t] - v;
        int gcol = b * 256 + t;
        float dv = v > 0 ? rsqrtf((float)v) : 0.f;
        ds[t] = dv;
        if (gcol < n2) {
            rowptr[gcol] = s + excl;
            dinv[gcol] = dv;
        }
        cur[t] = excl;
    }
    __syncthreads();
    for (int i = t; i < m; i += 512) {
        unsigned p = seg[i];
        int cl = (p >> 16) & 255;
        int pos = s + atomicAdd(&cur[cl], 1);
        csr[pos] = (unsigned short)(p & 0xFFFFu);
    }
    if (b == NB - 1 && t == 0) rowptr[n2] = e;
    // prescale tail: xsb rows for this bucket's gcols (8 elems/task)
    for (int k = t; k < 2048; k += 512) {
        int gl = k >> 3, segk = k & 7;
        int gcol = b * 256 + gl;
        if (gcol >= n2) continue;
        float d = ds[gl];
        int slice = gcol >= n;
        int row = gcol - slice * n;
        const float* xp = x + (size_t)row * 64 + segk * 8;
        float4 v0 = *(const float4*)xp;
        float4 v1 = *(const float4*)(xp + 4);
        uint4 o;
        o.x = pack2(v0.x * d, v0.y * d); o.y = pack2(v0.z * d, v0.w * d);
        o.z = pack2(v1.x * d, v1.y * d); o.w = pack2(v1.z * d, v1.w * d);
        *(uint4*)&xsb[(size_t)slice * n64 + (size_t)row * 64 + segk * 8] = o;
    }
}

// --- gather path ------------------------------------------------------------

// 8 lanes/node; 2-deep pipelined batches; predicated tail; slice->XCD affinity.
#define LOAD8(U, IDX)                                                       \
    do {                                                                    \
        _Pragma("unroll") for (int j = 0; j < 8; ++j) {                     \
            int r = __shfl((IDX), j, 8);                                    \
            (U)[j] = *(const uint4*)&mb[(size_t)r * 64 + l * 8];            \
        }                                                                   \
    } while (0)
#define ZPAD8(U, BB)                                                        \
    do {                                                                    \
        _Pragma("unroll") for (int j = 0; j < 8; ++j)                       \
            if ((BB) + j >= e) { (U)[j].x = 0; (U)[j].y = 0;                \
                                 (U)[j].z = 0; (U)[j].w = 0; }              \
    } while (0)
#define ACC8(U)                                                             \
    do {                                                                    \
        _Pragma("unroll") for (int j = 0; j < 8; ++j) {                     \
            a0 += uflo((U)[j].x); a1 += ufhi((U)[j].x);                     \
            a2 += uflo((U)[j].y); a3 += ufhi((U)[j].y);                     \
            a4 += uflo((U)[j].z); a5 += ufhi((U)[j].z);                     \
            a6 += uflo((U)[j].w); a7 += ufhi((U)[j].w);                     \
        }                                                                   \
    } while (0)

__global__ __launch_bounds__(256) void gatherbf_kernel(const int* __restrict__ rowptr,
                                                       const unsigned short* __restrict__ csr,
                                                       const unsigned short* __restrict__ xsb,
                                                       const float* __restrict__ dinv,
                                                       unsigned short* __restrict__ outb,
                                                       int n) {
    // XCD affinity: blocks with (bid&7)<4 -> slice 0, else slice 1
    int blk = blockIdx.x;
    int xcd = blk & 7;
    int slice = (xcd >= 4) ? 1 : 0;
    int rank = (blk >> 3) * 4 + (xcd & 3);
    int nodeLocal = rank * 32 + (threadIdx.x >> 3);
    if (nodeLocal >= n) return;
    int node = slice * n + nodeLocal;
    int l = threadIdx.x & 7;
    const unsigned short* mb = xsb + (size_t)slice * n * 64;
    int s = rowptr[node], e = rowptr[node + 1];
    float a0 = 0.f, a1 = 0.f, a2 = 0.f, a3 = 0.f, a4 = 0.f, a5 = 0.f, a6 = 0.f, a7 = 0.f;
    uint4 uA[8], uB[8];
    int b = s;
    if (b + 8 <= e) {
        int ia = csr[b + l];
        LOAD8(uA, ia);
        int bB = b + 8;
        int ib = (bB + l < e) ? (int)csr[bB + l] : 0;
        while (true) {
            bool hasB = (bB < e);
            if (hasB) {
                LOAD8(uB, ib);
                if (bB + 8 > e) ZPAD8(uB, bB);
            }
            int bA2 = bB + 8;
            if (bA2 < e) ia = (bA2 + l < e) ? (int)csr[bA2 + l] : 0;
            ACC8(uA);
            if (!hasB) break;
            bool hasA2 = (bA2 < e);
            if (hasA2) {
                LOAD8(uA, ia);
                if (bA2 + 8 > e) ZPAD8(uA, bA2);
            }
            int bB2 = bA2 + 8;
            if (bB2 < e) ib = (bB2 + l < e) ? (int)csr[bB2 + l] : 0;
            ACC8(uB);
            if (!hasA2) break;
            bB = bB2;
        }
    } else if (b < e) {
        int ia = (b + l < e) ? (int)csr[b + l] : 0;
        LOAD8(uA, ia);
        ZPAD8(uA, b);
        ACC8(uA);
    }
    float d = dinv[node];
    uint4 o;
    o.x = pack2(a0 * d, a1 * d);
    o.y = pack2(a2 * d, a3 * d);
    o.z = pack2(a4 * d, a5 * d);
    o.w = pack2(a6 * d, a7 * d);
    *(uint4*)&outb[(size_t)node * 64 + l * 8] = o;
}

// --- de-staged MFMA GEMMs ---------------------------------------------------

// Cb[2n,F] bf16 = Ab[2n,64] @ W_slice; fused BN stats; LDS-transposed C write.
template <int F>
__global__ __launch_bounds__(256) void mfma_gemmb(const unsigned short* __restrict__ Ab,
                                                  const unsigned* __restrict__ WT0,
                                                  const unsigned* __restrict__ WT1,
                                                  unsigned short* __restrict__ Cb,
                                                  float* __restrict__ sums_base,
                                                  int roff, int n) {
    constexpr int NC = F / 16;
    __shared__ float ls[2 * F];
    __shared__ unsigned short stb[64 * F];
    int BPS = (n + 63) >> 6;
    int slice = blockIdx.x >= BPS;
    int sb = blockIdx.x - slice * BPS;
    const unsigned* WT = slice ? WT1 : WT0;
    int row0 = slice * n + sb * 64;
    int rows = min(64, n - sb * 64);
    for (int i = threadIdx.x; i < 2 * F; i += 256) ls[i] = 0.f;
    int w = threadIdx.x >> 6, lane = threadIdx.x & 63, q = lane >> 4, ln = lane & 15;
    const unsigned* A32 = (const unsigned*)Ab;
    size_t arow = (size_t)(row0 + 16 * w + ln) * 32;
    v8s af0 = *(const v8s*)&A32[arow + q * 4];
    v8s af1 = *(const v8s*)&A32[arow + 16 + q * 4];
    f32x4 acc[NC];
#pragma unroll
    for (int ct = 0; ct < NC; ++ct) acc[ct] = {0.f, 0.f, 0.f, 0.f};
#pragma unroll
    for (int ct = 0; ct < NC; ++ct) {
        v8s b0 = *(const v8s*)&WT[(ct * 16 + ln) * 32 + q * 4];
        v8s b1 = *(const v8s*)&WT[(ct * 16 + ln) * 32 + 16 + q * 4];
        acc[ct] = __builtin_amdgcn_mfma_f32_16x16x32_bf16(af0, b0, acc[ct], 0, 0, 0);
        acc[ct] = __builtin_amdgcn_mfma_f32_16x16x32_bf16(af1, b1, acc[ct], 0, 0, 0);
    }
    __syncthreads();  // ls zero-init visible
#pragma unroll
    for (int ct = 0; ct < NC; ++ct) {
        float s1 = 0.f, s2 = 0.f;
        int cc = ct * 16 + ln;
#pragma unroll
        for (int i = 0; i < 4; ++i) {
            int r = 16 * w + q * 4 + i;
            stb[r * F + (cc ^ ((r & 7) << 3))] = bf16of(acc[ct][i]);
            if (r < rows) {
                float v = acc[ct][i];
                s1 += v;
                s2 += v * v;
            }
        }
        s1 += __shfl_xor(s1, 16); s1 += __shfl_xor(s1, 32);
        s2 += __shfl_xor(s2, 16); s2 += __shfl_xor(s2, 32);
        if (q == 0) {
            atomicAdd(&ls[cc], s1);
            atomicAdd(&ls[F + cc], s2);
        }
    }
    __syncthreads();  // stb + ls complete
    {
        constexpr int CPT = F / 4;
        int rr = threadIdx.x >> 2, sg = threadIdx.x & 3;
        if (rr < rows) {
            int swz = (rr & 7) << 3;
            int cb = sg * CPT;
            uint4* dst = (uint4*)(Cb + (size_t)(row0 + rr) * F + cb);
#pragma unroll
            for (int jj = 0; jj < CPT / 8; ++jj)
                dst[jj] = *(const uint4*)&stb[rr * F + ((cb + jj * 8) ^ swz)];
        }
    }
    if (threadIdx.x < F) {
        float* dst = sums_base + (blockIdx.x & 7) * 1024 + roff + slice * 2 * F;
        unsafeAtomicAdd(&dst[threadIdx.x], ls[threadIdx.x]);
        unsafeAtomicAdd(&dst[F + threadIdx.x], ls[F + threadIdx.x]);
    }
}

// h1 = san(relu(bn(t0b)) + x); BN finalize fused (from sums); 8 elems/thread.
__global__ __launch_bounds__(256) void apply0_kernel(const unsigned short* __restrict__ t0b,
                                                     const float* __restrict__ x,
                                                     const float* __restrict__ sums_base,
                                                     const float* __restrict__ g,
                                                     const float* __restrict__ be,
                                                     const float* __restrict__ dinv,
                                                     unsigned short* __restrict__ h1b,
                                                     unsigned short* __restrict__ h1sb,
                                                     int n64, int total, int n) {
    __shared__ float sc[256];  // [slice*128 + {f, 64+f}]
    int t = threadIdx.x;
    if (t < 128) {  // fused bnfinal<64>, both slices
        int slice = t >> 6, f = t & 63;
        float s1 = 0.f, s2 = 0.f;
#pragma unroll
        for (int r = 0; r < 8; ++r) {
            const float* src = sums_base + r * 1024 + 512 + slice * 128;
            s1 += src[f];
            s2 += src[64 + f];
        }
        float inv_n = 1.0f / (float)n;
        float mu = s1 * inv_n;
        float var = fmaxf(s2 * inv_n - mu * mu, 0.f);
        float scale = g[f] * rsqrtf(var + 1e-5f);
        sc[slice * 128 + f] = scale;
        sc[slice * 128 + 64 + f] = be[f] - mu * scale;
    }
    __syncthreads();
    int i8 = (blockIdx.x * 256 + t) * 8;
    if (i8 >= total) return;
    int slice = i8 >= n64;
    int f0 = i8 & 63;
    const float* scp = sc + slice * 128;
    uint4 tv = *(const uint4*)&t0b[i8];
    const float* xp = x + (i8 - slice * n64);
    float4 x0 = *(const float4*)xp;
    float4 x1 = *(const float4*)(xp + 4);
    float4 s0 = *(const float4*)&scp[f0];
    float4 s1 = *(const float4*)&scp[f0 + 4];
    float4 g0 = *(const float4*)&scp[64 + f0];
    float4 g1 = *(const float4*)&scp[64 + f0 + 4];
    float d = dinv[i8 >> 6];
    float tvv[8] = {uflo(tv.x), ufhi(tv.x), uflo(tv.y), ufhi(tv.y),
                    uflo(tv.z), ufhi(tv.z), uflo(tv.w), ufhi(tv.w)};
    float sa[8] = {s0.x, s0.y, s0.z, s0.w, s1.x, s1.y, s1.z, s1.w};
    float sh[8] = {g0.x, g0.y, g0.z, g0.w, g1.x, g1.y, g1.z, g1.w};
    float xv[8] = {x0.x, x0.y, x0.z, x0.w, x1.x, x1.y, x1.z, x1.w};
    unsigned po[4], ps[4];
#pragma unroll
    for (int j = 0; j < 4; ++j) {
        float a = sanf(fmaxf(fmaf(tvv[2 * j], sa[2 * j], sh[2 * j]), 0.f) + xv[2 * j]);
        float b = sanf(fmaxf(fmaf(tvv[2 * j + 1], sa[2 * j + 1], sh[2 * j + 1]), 0.f) + xv[2 * j + 1]);
        po[j] = pack2(a, b);
        ps[j] = pack2(a * d, b * d);
    }
    *(uint4*)&h1b[i8] = *(uint4*)po;
    *(uint4*)&h1sb[i8] = *(uint4*)ps;
}

// --- fused apply1 + head: comb lives in LDS ---------------------------------
// Per row-tile: BN-finalize (slice scales), then for slice 0/1: res-GEMM ->
// f32 LDS stage -> vector epilogue -> bf16 comb in LDS (XOR-swizzled), then
// head fc1-MFMA (A from LDS) + fc2 + softmax. comb never touches global.
__global__ __launch_bounds__(256) void apply1_head(const unsigned short* __restrict__ h1b,
                                                   const unsigned short* __restrict__ Tb,
                                                   const unsigned* __restrict__ RT0,
                                                   const unsigned* __restrict__ RT1,
                                                   const unsigned* __restrict__ FT,
                                                   const float* __restrict__ sums_base,
                                                   const float* __restrict__ g,
                                                   const float* __restrict__ be,
                                                   const float* __restrict__ fc1_b,
                                                   const float* __restrict__ w2,
                                                   const float* __restrict__ b2,
                                                   float* __restrict__ out, int n) {
    __shared__ float st[64 * 128];            // 32 KB f32 C-stage (reused per slice)
    __shared__ unsigned short cmb[64 * 256];  // 32 KB bf16 comb, XOR-swizzled
    __shared__ float scl[512];                // per-slice scale[128]+shift[128]
    int t = threadIdx.x;
    int row0l = blockIdx.x * 64;
    int rows = min(64, n - row0l);
    {   // fused bnfinal<128>, both slices (roff 0)
        int slice = t >> 7, f = t & 127;
        float s1 = 0.f, s2 = 0.f;
#pragma unroll
        for (int r = 0; r < 8; ++r) {
            const float* src = sums_base + r * 1024 + slice * 256;
            s1 += src[f];
            s2 += src[128 + f];
        }
        float inv_n = 1.0f / (float)n;
        float mu = s1 * inv_n;
        float var = fmaxf(s2 * inv_n - mu * mu, 0.f);
        float scale = g[f] * rsqrtf(var + 1e-5f);
        scl[slice * 256 + f] = scale;
        scl[slice * 256 + 128 + f] = be[f] - mu * scale;
    }
    int w = t >> 6, lane = t & 63, q = lane >> 4, ln = lane & 15;
#pragma unroll
    for (int slice = 0; slice < 2; ++slice) {
        const unsigned* WT = slice ? RT1 : RT0;
        int row0 = slice * n + row0l;
        const unsigned* A32 = (const unsigned*)h1b;
        size_t arow = (size_t)(row0 + 16 * w + ln) * 32;
        v8s af0 = *(const v8s*)&A32[arow + q * 4];
        v8s af1 = *(const v8s*)&A32[arow + 16 + q * 4];
        f32x4 acc[8];
#pragma unroll
        for (int ct = 0; ct < 8; ++ct) acc[ct] = {0.f, 0.f, 0.f, 0.f};
#pragma unroll
        for (int ct = 0; ct < 8; ++ct) {
            v8s b0 = *(const v8s*)&WT[(ct * 16 + ln) * 32 + q * 4];
            v8s b1 = *(const v8s*)&WT[(ct * 16 + ln) * 32 + 16 + q * 4];
            acc[ct] = __builtin_amdgcn_mfma_f32_16x16x32_bf16(af0, b0, acc[ct], 0, 0, 0);
            acc[ct] = __builtin_amdgcn_mfma_f32_16x16x32_bf16(af1, b1, acc[ct], 0, 0, 0);
        }
#pragma unroll
        for (int ct = 0; ct < 8; ++ct) {
            int cc = ct * 16 + ln;
#pragma unroll
            for (int i = 0; i < 4; ++i) {
                int r = 16 * w + q * 4 + i;
                st[r * 128 + (cc ^ ((r & 7) << 2))] = acc[ct][i];
            }
        }
        __syncthreads();  // st staged (+ scl ready on first pass)
        int rr = t >> 2, sg = t & 3;
        if (rr < rows) {
            int swz = (rr & 7) << 2;          // f32-word XOR for st
            int swzB = (rr & 7) << 4;         // byte XOR for cmb
            int rg = row0 + rr;
            const uint4* tbp = (const uint4*)(Tb + (size_t)rg * 128 + sg * 32);
            const float* scb = scl + slice * 256 + sg * 32;
            char* cp = (char*)(cmb + rr * 256);
#pragma unroll
            for (int jj = 0; jj < 4; ++jj) {
                uint4 tv = tbp[jj];
                int base = sg * 32 + jj * 8;
                float4 a0 = *(const float4*)&st[rr * 128 + (base ^ swz)];
                float4 a1 = *(const float4*)&st[rr * 128 + ((base + 4) ^ swz)];
                float4 s0 = *(const float4*)&scb[jj * 8];
                float4 s1 = *(const float4*)&scb[jj * 8 + 4];
                float4 h0 = *(const float4*)&scb[128 + jj * 8];
                float4 h1v = *(const float4*)&scb[128 + jj * 8 + 4];
                float o0 = sanf(fmaf(uflo(tv.x), s0.x, h0.x) + a0.x);
                float o1 = sanf(fmaf(ufhi(tv.x), s0.y, h0.y) + a0.y);
                float o2 = sanf(fmaf(uflo(tv.y), s0.z, h0.z) + a0.z);
                float o3 = sanf(fmaf(ufhi(tv.y), s0.w, h0.w) + a0.w);
                float o4 = sanf(fmaf(uflo(tv.z), s1.x, h1v.x) + a1.x);
                float o5 = sanf(fmaf(ufhi(tv.z), s1.y, h1v.y) + a1.y);
                float o6 = sanf(fmaf(uflo(tv.w), s1.z, h1v.z) + a1.z);
                float o7 = sanf(fmaf(ufhi(tv.w), s1.w, h1v.w) + a1.w);
                uint4 ov;
                ov.x = pack2(o0, o1);
                ov.y = pack2(o2, o3);
                ov.z = pack2(o4, o5);
                ov.w = pack2(o6, o7);
                *(uint4*)(cp + ((slice * 256 + sg * 64 + jj * 16) ^ swzB)) = ov;
            }
        }
        __syncthreads();  // epilogue done; st free; cmb half complete
    }
    // ---- head: fc1 MFMA (A from LDS cmb) + relu + fc2 + softmax ----
    {
        int rowLocal = 16 * w + ln;
        const char* cr = (const char*)(cmb + rowLocal * 256);
        int swzR = (rowLocal & 7) << 4;
        f32x4 acc[8];
#pragma unroll
        for (int ct = 0; ct < 8; ++ct) acc[ct] = {0.f, 0.f, 0.f, 0.f};
#pragma unroll
        for (int kt = 0; kt < 4; ++kt) {
            v8s af0 = *(const v8s*)(cr + ((kt * 128 + q * 16) ^ swzR));
            v8s af1 = *(const v8s*)(cr + ((kt * 128 + 64 + q * 16) ^ swzR));
#pragma unroll
            for (int ct = 0; ct < 8; ++ct) {
                v8s b0 = *(const v8s*)&FT[(ct * 16 + ln) * 128 + kt * 32 + q * 4];
                v8s b1 = *(const v8s*)&FT[(ct * 16 + ln) * 128 + kt * 32 + 16 + q * 4];
                acc[ct] = __builtin_amdgcn_mfma_f32_16x16x32_bf16(af0, b0, acc[ct], 0, 0, 0);
                acc[ct] = __builtin_amdgcn_mfma_f32_16x16x32_bf16(af1, b1, acc[ct], 0, 0, 0);
            }
        }
        float p0[4] = {0.f, 0.f, 0.f, 0.f}, p1[4] = {0.f, 0.f, 0.f, 0.f};
#pragma unroll
        for (int ct = 0; ct < 8; ++ct) {
            int c = ct * 16 + ln;
            float bi = fc1_b[c];
            float w20 = w2[c * 2], w21 = w2[c * 2 + 1];
#pragma unroll
            for (int i = 0; i < 4; ++i) {
                float h = fmaxf(acc[ct][i] + bi, 0.f);
                p0[i] = fmaf(h, w20, p0[i]);
                p1[i] = fmaf(h, w21, p1[i]);
            }
        }
#pragma unroll
        for (int i = 0; i < 4; ++i) {
#pragma unroll
            for (int msk = 1; msk < 16; msk <<= 1) {
                p0[i] += __shfl_xor(p0[i], msk);
                p1[i] += __shfl_xor(p1[i], msk);
            }
        }
        if (ln == 0) {
            float bb0 = b2[0], bb1 = b2[1];
#pragma unroll
            for (int i = 0; i < 4; ++i) {
                int r = 16 * w + q * 4 + i;
                if (r >= rows) continue;
                int R = row0l + r;
                float l0 = p0[i] + bb0, l1 = p1[i] + bb1;
                float mx = fmaxf(l0, l1);
                float e0 = expf(l0 - mx), e1 = expf(l1 - mx);
                float inv = 1.0f / (e0 + e1);
                out[(size_t)R * 2] = l0;
                out[(size_t)R * 2 + 1] = l1;
                out[(size_t)2 * n + R * 2] = e0 * inv;
                out[(size_t)2 * n + R * 2 + 1] = e1 * inv;
            }
        }
    }
}

static inline int cdiv(int a, int b) { return (a + b - 1) / b; }

extern "C" void kernel_launch(void* const* d_in, const int* in_sizes, int n_in,
                              void* d_out, int out_size, void* d_ws, size_t ws_size,
                              hipStream_t stream) {
    const float* x       = (const float*)d_in[0];
    const int*   ei0     = (const int*)d_in[1];
    const int*   ei1     = (const int*)d_in[2];
    const float* w0_s0   = (const float*)d_in[3];
    const float* w1_s0   = (const float*)d_in[5];
    const float* res1_s0 = (const float*)d_in[7];
    const float* w0_s1   = (const float*)d_in[8];
    const float* w1_s1   = (const float*)d_in[10];
    const float* res1_s1 = (const float*)d_in[12];
    const float* bn_g0   = (const float*)d_in[13];
    const float* bn_b0   = (const float*)d_in[14];
    const float* bn_g1   = (const float*)d_in[15];
    const float* bn_b1   = (const float*)d_in[16];
    const float* fc1_w   = (const float*)d_in[17];
    const float* fc1_b   = (const float*)d_in[18];
    const float* fc2_w   = (const float*)d_in[19];
    const float* fc2_b   = (const float*)d_in[20];
    float* out = (float*)d_out;

    int n = in_sizes[0] / 64;   // 50000
    int E = in_sizes[1] / 2;    // 1600000
    int n2 = 2 * n, E2 = 2 * E;
    int n64 = n * 64;
    int NB = cdiv(n2, 256);     // 391 buckets (256 cols each)
    int BPS = cdiv(n, 64);      // 782 row-tiles per slice
    int GB = 8 * cdiv(cdiv(n, 32), 4);  // gather grid: XCD-affine, 32 nodes/block

    float* X1 = (float*)d_ws;                       // t0b/Tb region (2n*128 u16 max)
    float* S  = X1 + (size_t)n2 * 64;               // h1sb region
    unsigned short* Gb   = (unsigned short*)(S + (size_t)n2 * 64);
    unsigned short* h1b  = Gb + (size_t)n2 * 64;
    unsigned short* comb = h1b + (size_t)n2 * 64;   // binned overlay region only
    unsigned short* xsb  = comb + (size_t)n * 256;  // n*128 u16
    float* dinv = (float*)(xsb + (size_t)n * 128);
    float* sums = dinv + n2;                        // [8][1024] replicas
    float* scsh = sums + 8192;                      // (layout spacer)
    unsigned* wpk = (unsigned*)(scsh + 512);        // [36864]
    unsigned short* csr = (unsigned short*)(wpk + 36864);  // [E2] u16
    int* rowptr = (int*)(csr + (size_t)E2);
    int* bcnt   = rowptr + (n2 + 1);                // [512]
    unsigned short* t0b = (unsigned short*)X1;
    unsigned short* Tb  = (unsigned short*)X1;
    unsigned* binned = (unsigned*)comb;
    unsigned short* h1sb = (unsigned short*)S;
    unsigned* w0T0 = wpk + 0,    *w0T1 = wpk + 2048;
    unsigned* w1T0 = wpk + 4096, *w1T1 = wpk + 8192;
    unsigned* rT0  = wpk + 12288,*rT1  = wpk + 16384;
    unsigned* fT   = wpk + 20480;

    // --- prep (weight pack + zero bcnt/sums) + CSR build (+prescale tail) ---
    prep_kernel<<<144, 256, 0, stream>>>(w0_s0, w0_s1, w1_s0, w1_s1,
                                         res1_s0, res1_s1, fc1_w, wpk, bcnt, sums);
    kC_bin<<<cdiv(E2, 8192), 512, 0, stream>>>(ei0, ei1, bcnt, binned, E, n);
    kD_build<<<NB, 512, 0, stream>>>(binned, bcnt, x, rowptr, dinv, csr, xsb, n2, NB);

    // --- layer 0 ---
    gatherbf_kernel<<<GB, 256, 0, stream>>>(rowptr, csr, xsb, dinv, Gb, n);
    mfma_gemmb<64><<<2 * BPS, 256, 0, stream>>>(Gb, w0T0, w0T1, t0b, sums, 512, n);
    apply0_kernel<<<cdiv(2 * n64, 2048), 256, 0, stream>>>(t0b, x, sums, bn_g0, bn_b0,
                                                           dinv, h1b, h1sb, n64, 2 * n64, n);

    // --- layer 1 ---
    gatherbf_kernel<<<GB, 256, 0, stream>>>(rowptr, csr, h1sb, dinv, Gb, n);
    mfma_gemmb<128><<<2 * BPS, 256, 0, stream>>>(Gb, w1T0, w1T1, Tb, sums, 0, n);

    // --- fused apply1 + head (comb in LDS) ---
    apply1_head<<<BPS, 256, 0, stream>>>(h1b, Tb, rT0, rT1, fT, sums, bn_g1, bn_b1,
                                         fc1_b, fc2_w, fc2_b, out, n);
}

// Round 7
// 342.825 us; speedup vs baseline: 3.2188x; 1.0128x over previous
//
#include <hip/hip_runtime.h>
#include <hip/hip_bf16.h>
#include <math.h>

// ---------------------------------------------------------------------------
// DriverGeneGNN: 2-slice GCN (64->64->128) + BN + residual + MLP head.
// N=50000, E=1600000. fp32 accumulate, bf16 operands + bf16 intermediates.
// R19: apply1_head occupancy fix (61us @ 14% occ, LDS 67.5KB -> 2 blk/CU).
//      mfma_gemmb<128> now stores C in raw MFMA FRAGMENT layout (Tfrag,
//      per-lane uint2, coalesced, no LDS transpose) -- apply1_head reads it
//      vectorized in the SAME (tile,wave,lane) decomposition, applies
//      BN+residual+san on the acc registers, writes bf16 directly into the
//      swizzled cmb LDS. Deletes the 32KB f32 st stage: LDS 34.8KB -> 4
//      blk/CU. gemm128 loses its stb stage too (1KB LDS, coalesced store).
// R18: kernel boundary IS the cheap grid barrier (R17 coop grid.sync = L2
//      flush disaster); prescale folded into kD; comb lives in LDS.
// R16: latency-bound gather never fused with LDS-heavy MFMA (occupancy).
// MFMA frag layouts (HW-verified): A[m=lane&15][k=(lane>>4)*8+j],
//     B[k][n=lane&15], C/D col=lane&15 row=(lane>>4)*4+reg.
// Conv biases cancel in BN -> skipped.
// ---------------------------------------------------------------------------

typedef short v8s __attribute__((ext_vector_type(8)));
typedef float f32x4 __attribute__((ext_vector_type(4)));

#define BSTRIDE 10240  // u32 slots per 256-col bucket segment (mean 8184)

__device__ __forceinline__ float sanf(float v) {
    if (v != v) return 0.f;
    if (isinf(v)) return v > 0.f ? 100.f : -100.f;
    return v;
}

__device__ __forceinline__ unsigned short bf16of(float v) {
    __hip_bfloat16 h = __float2bfloat16(v);
    return *(unsigned short*)&h;
}
__device__ __forceinline__ unsigned pack2(float lo, float hi) {
    return (unsigned)bf16of(lo) | ((unsigned)bf16of(hi) << 16);
}
__device__ __forceinline__ float uflo(unsigned u) { return __uint_as_float(u << 16); }
__device__ __forceinline__ float ufhi(unsigned u) { return __uint_as_float(u & 0xFFFF0000u); }

// --- prep: pack weights as W^T bf16-pairs + zero bcnt/sums ------------------
__device__ __forceinline__ void packone(const float* __restrict__ src, unsigned* __restrict__ dst,
                                        int L, int Khalf, int F) {
    int c = L / Khalf, kp = L - c * Khalf;
    dst[L] = pack2(src[(2 * kp) * F + c], src[(2 * kp + 1) * F + c]);
}

__global__ __launch_bounds__(256) void prep_kernel(const float* __restrict__ w0_0,
                                                   const float* __restrict__ w0_1,
                                                   const float* __restrict__ w1_0,
                                                   const float* __restrict__ w1_1,
                                                   const float* __restrict__ r_0,
                                                   const float* __restrict__ r_1,
                                                   const float* __restrict__ fc1,
                                                   unsigned* __restrict__ wpk,
                                                   int* __restrict__ bcnt,
                                                   float* __restrict__ sums) {
    int gid = blockIdx.x * 256 + threadIdx.x;
    if (gid < 512) bcnt[gid] = 0;
    if (gid < 8192) sums[gid] = 0.f;
    if (gid < 2048)       packone(w0_0, wpk + 0,     gid - 0,     32, 64);
    else if (gid < 4096)  packone(w0_1, wpk + 2048,  gid - 2048,  32, 64);
    else if (gid < 8192)  packone(w1_0, wpk + 4096,  gid - 4096,  32, 128);
    else if (gid < 12288) packone(w1_1, wpk + 8192,  gid - 8192,  32, 128);
    else if (gid < 16384) packone(r_0,  wpk + 12288, gid - 12288, 32, 128);
    else if (gid < 20480) packone(r_1,  wpk + 16384, gid - 16384, 32, 128);
    else if (gid < 36864) packone(fc1,  wpk + 20480, gid - 20480, 128, 128);
}

// --- CSR build --------------------------------------------------------------

__global__ __launch_bounds__(512) void kC_bin(const int* __restrict__ ei0,
                                              const int* __restrict__ ei1,
                                              int* __restrict__ bcnt,
                                              unsigned* __restrict__ binned,
                                              int E, int n) {
    __shared__ int cnt[512];
    __shared__ int base[512];
    int t = threadIdx.x;
    cnt[t] = 0;
    int E2 = 2 * E;
    int e0 = blockIdx.x * 8192;
    unsigned pk[16];
    int bk[16];
    __syncthreads();
#pragma unroll
    for (int j = 0; j < 16; ++j) {
        int ge = e0 + t + j * 512;
        bk[j] = -1;
        if (ge < E2) {
            int slice = ge >= E;
            const int* ei = slice ? ei1 : ei0;
            int e = ge - slice * E;
            int col = ei[E + e], row = ei[e];
            int gcol = slice * n + col;
            bk[j] = gcol >> 8;
            pk[j] = (unsigned)row | (((unsigned)gcol & 255u) << 16);
            atomicAdd(&cnt[bk[j]], 1);
        }
    }
    __syncthreads();
    {
        int c = cnt[t];
        base[t] = c ? atomicAdd(&bcnt[t], c) : 0;
    }
    __syncthreads();
    cnt[t] = 0;
    __syncthreads();
#pragma unroll
    for (int j = 0; j < 16; ++j) {
        if (bk[j] >= 0) {
            int loc = atomicAdd(&cnt[bk[j]], 1);
            int off = base[bk[j]] + loc;
            if (off < BSTRIDE) binned[(size_t)bk[j] * BSTRIDE + off] = pk[j];
        }
    }
}

// one block (512 thr) per 256-col bucket; per-block scan of bcnt (kB fused);
// prescale tail fused: this block owns dinv for its gcols -> write xsb rows.
__global__ __launch_bounds__(512) void kD_build(const unsigned* __restrict__ binned,
                                                const int* __restrict__ bcnt,
                                                const float* __restrict__ x,
                                                int* __restrict__ rowptr,
                                                float* __restrict__ dinv,
                                                unsigned short* __restrict__ csr,
                                                unsigned short* __restrict__ xsb,
                                                int n2, int NB) {
    __shared__ int pref[512];
    __shared__ int cnt[256];
    __shared__ int scn[256];
    __shared__ int cur[256];
    __shared__ float ds[256];
    int b = blockIdx.x, t = threadIdx.x;
    int n = n2 >> 1, n64 = n * 64;
    // inclusive scan of bcnt[0..NB) in LDS (NB <= 512)
    pref[t] = (t < NB) ? bcnt[t] : 0;
    __syncthreads();
    for (int off = 1; off < 512; off <<= 1) {
        int u = (t >= off) ? pref[t - off] : 0;
        __syncthreads();
        pref[t] += u;
        __syncthreads();
    }
    int s = (b > 0) ? pref[b - 1] : 0;
    int e = pref[b];
    int m = e - s;
    const unsigned* seg = binned + (size_t)b * BSTRIDE;
    if (t < 256) cnt[t] = 0;
    __syncthreads();
    for (int i = t; i < m; i += 512) atomicAdd(&cnt[(seg[i] >> 16) & 255], 1);
    __syncthreads();
    int v = (t < 256) ? cnt[t] : 0;
    if (t < 256) scn[t] = v;
    __syncthreads();
    for (int off = 1; off < 256; off <<= 1) {
        int u = (t < 256 && t >= off) ? scn[t - off] : 0;
        __syncthreads();
        if (t < 256) scn[t] += u;
        __syncthreads();
    }
    if (t < 256) {
        int excl = scn[t] - v;
        int gcol = b * 256 + t;
        float dv = v > 0 ? rsqrtf((float)v) : 0.f;
        ds[t] = dv;
        if (gcol < n2) {
            rowptr[gcol] = s + excl;
            dinv[gcol] = dv;
        }
        cur[t] = excl;
    }
    __syncthreads();
    for (int i = t; i < m; i += 512) {
        unsigned p = seg[i];
        int cl = (p >> 16) & 255;
        int pos = s + atomicAdd(&cur[cl], 1);
        csr[pos] = (unsigned short)(p & 0xFFFFu);
    }
    if (b == NB - 1 && t == 0) rowptr[n2] = e;
    // prescale tail: xsb rows for this bucket's gcols (8 elems/task)
    for (int k = t; k < 2048; k += 512) {
        int gl = k >> 3, segk = k & 7;
        int gcol = b * 256 + gl;
        if (gcol >= n2) continue;
        float d = ds[gl];
        int slice = gcol >= n;
        int row = gcol - slice * n;
        const float* xp = x + (size_t)row * 64 + segk * 8;
        float4 v0 = *(const float4*)xp;
        float4 v1 = *(const float4*)(xp + 4);
        uint4 o;
        o.x = pack2(v0.x * d, v0.y * d); o.y = pack2(v0.z * d, v0.w * d);
        o.z = pack2(v1.x * d, v1.y * d); o.w = pack2(v1.z * d, v1.w * d);
        *(uint4*)&xsb[(size_t)slice * n64 + (size_t)row * 64 + segk * 8] = o;
    }
}

// --- gather path ------------------------------------------------------------

// 8 lanes/node; 2-deep pipelined batches; predicated tail; slice->XCD affinity.
#define LOAD8(U, IDX)                                                       \
    do {                                                                    \
        _Pragma("unroll") for (int j = 0; j < 8; ++j) {                     \
            int r = __shfl((IDX), j, 8);                                    \
            (U)[j] = *(const uint4*)&mb[(size_t)r * 64 + l * 8];            \
        }                                                                   \
    } while (0)
#define ZPAD8(U, BB)                                                        \
    do {                                                                    \
        _Pragma("unroll") for (int j = 0; j < 8; ++j)                       \
            if ((BB) + j >= e) { (U)[j].x = 0; (U)[j].y = 0;                \
                                 (U)[j].z = 0; (U)[j].w = 0; }              \
    } while (0)
#define ACC8(U)                                                             \
    do {                                                                    \
        _Pragma("unroll") for (int j = 0; j < 8; ++j) {                     \
            a0 += uflo((U)[j].x); a1 += ufhi((U)[j].x);                     \
            a2 += uflo((U)[j].y); a3 += ufhi((U)[j].y);                     \
            a4 += uflo((U)[j].z); a5 += ufhi((U)[j].z);                     \
            a6 += uflo((U)[j].w); a7 += ufhi((U)[j].w);                     \
        }                                                                   \
    } while (0)

__global__ __launch_bounds__(256) void gatherbf_kernel(const int* __restrict__ rowptr,
                                                       const unsigned short* __restrict__ csr,
                                                       const unsigned short* __restrict__ xsb,
                                                       const float* __restrict__ dinv,
                                                       unsigned short* __restrict__ outb,
                                                       int n) {
    // XCD affinity: blocks with (bid&7)<4 -> slice 0, else slice 1
    int blk = blockIdx.x;
    int xcd = blk & 7;
    int slice = (xcd >= 4) ? 1 : 0;
    int rank = (blk >> 3) * 4 + (xcd & 3);
    int nodeLocal = rank * 32 + (threadIdx.x >> 3);
    if (nodeLocal >= n) return;
    int node = slice * n + nodeLocal;
    int l = threadIdx.x & 7;
    const unsigned short* mb = xsb + (size_t)slice * n * 64;
    int s = rowptr[node], e = rowptr[node + 1];
    float a0 = 0.f, a1 = 0.f, a2 = 0.f, a3 = 0.f, a4 = 0.f, a5 = 0.f, a6 = 0.f, a7 = 0.f;
    uint4 uA[8], uB[8];
    int b = s;
    if (b + 8 <= e) {
        int ia = csr[b + l];
        LOAD8(uA, ia);
        int bB = b + 8;
        int ib = (bB + l < e) ? (int)csr[bB + l] : 0;
        while (true) {
            bool hasB = (bB < e);
            if (hasB) {
                LOAD8(uB, ib);
                if (bB + 8 > e) ZPAD8(uB, bB);
            }
            int bA2 = bB + 8;
            if (bA2 < e) ia = (bA2 + l < e) ? (int)csr[bA2 + l] : 0;
            ACC8(uA);
            if (!hasB) break;
            bool hasA2 = (bA2 < e);
            if (hasA2) {
                LOAD8(uA, ia);
                if (bA2 + 8 > e) ZPAD8(uA, bA2);
            }
            int bB2 = bA2 + 8;
            if (bB2 < e) ib = (bB2 + l < e) ? (int)csr[bB2 + l] : 0;
            ACC8(uB);
            if (!hasA2) break;
            bB = bB2;
        }
    } else if (b < e) {
        int ia = (b + l < e) ? (int)csr[b + l] : 0;
        LOAD8(uA, ia);
        ZPAD8(uA, b);
        ACC8(uA);
    }
    float d = dinv[node];
    uint4 o;
    o.x = pack2(a0 * d, a1 * d);
    o.y = pack2(a2 * d, a3 * d);
    o.z = pack2(a4 * d, a5 * d);
    o.w = pack2(a6 * d, a7 * d);
    *(uint4*)&outb[(size_t)node * 64 + l * 8] = o;
}

// --- layer-0 MFMA GEMM (row-major C via LDS transpose; fused BN stats) ------
__global__ __launch_bounds__(256) void mfma_gemmb64(const unsigned short* __restrict__ Ab,
                                                    const unsigned* __restrict__ WT0,
                                                    const unsigned* __restrict__ WT1,
                                                    unsigned short* __restrict__ Cb,
                                                    float* __restrict__ sums_base,
                                                    int roff, int n) {
    constexpr int F = 64;
    constexpr int NC = F / 16;
    __shared__ float ls[2 * F];
    __shared__ unsigned short stb[64 * F];
    int BPS = (n + 63) >> 6;
    int slice = blockIdx.x >= BPS;
    int sb = blockIdx.x - slice * BPS;
    const unsigned* WT = slice ? WT1 : WT0;
    int row0 = slice * n + sb * 64;
    int rows = min(64, n - sb * 64);
    for (int i = threadIdx.x; i < 2 * F; i += 256) ls[i] = 0.f;
    int w = threadIdx.x >> 6, lane = threadIdx.x & 63, q = lane >> 4, ln = lane & 15;
    const unsigned* A32 = (const unsigned*)Ab;
    size_t arow = (size_t)(row0 + 16 * w + ln) * 32;
    v8s af0 = *(const v8s*)&A32[arow + q * 4];
    v8s af1 = *(const v8s*)&A32[arow + 16 + q * 4];
    f32x4 acc[NC];
#pragma unroll
    for (int ct = 0; ct < NC; ++ct) acc[ct] = {0.f, 0.f, 0.f, 0.f};
#pragma unroll
    for (int ct = 0; ct < NC; ++ct) {
        v8s b0 = *(const v8s*)&WT[(ct * 16 + ln) * 32 + q * 4];
        v8s b1 = *(const v8s*)&WT[(ct * 16 + ln) * 32 + 16 + q * 4];
        acc[ct] = __builtin_amdgcn_mfma_f32_16x16x32_bf16(af0, b0, acc[ct], 0, 0, 0);
        acc[ct] = __builtin_amdgcn_mfma_f32_16x16x32_bf16(af1, b1, acc[ct], 0, 0, 0);
    }
    __syncthreads();  // ls zero-init visible
#pragma unroll
    for (int ct = 0; ct < NC; ++ct) {
        float s1 = 0.f, s2 = 0.f;
        int cc = ct * 16 + ln;
#pragma unroll
        for (int i = 0; i < 4; ++i) {
            int r = 16 * w + q * 4 + i;
            stb[r * F + (cc ^ ((r & 7) << 3))] = bf16of(acc[ct][i]);
            if (r < rows) {
                float v = acc[ct][i];
                s1 += v;
                s2 += v * v;
            }
        }
        s1 += __shfl_xor(s1, 16); s1 += __shfl_xor(s1, 32);
        s2 += __shfl_xor(s2, 16); s2 += __shfl_xor(s2, 32);
        if (q == 0) {
            atomicAdd(&ls[cc], s1);
            atomicAdd(&ls[F + cc], s2);
        }
    }
    __syncthreads();  // stb + ls complete
    {
        constexpr int CPT = F / 4;
        int rr = threadIdx.x >> 2, sg = threadIdx.x & 3;
        if (rr < rows) {
            int swz = (rr & 7) << 3;
            int cb = sg * CPT;
            uint4* dst = (uint4*)(Cb + (size_t)(row0 + rr) * F + cb);
#pragma unroll
            for (int jj = 0; jj < CPT / 8; ++jj)
                dst[jj] = *(const uint4*)&stb[rr * F + ((cb + jj * 8) ^ swz)];
        }
    }
    if (threadIdx.x < F) {
        float* dst = sums_base + (blockIdx.x & 7) * 1024 + roff + slice * 2 * F;
        unsafeAtomicAdd(&dst[threadIdx.x], ls[threadIdx.x]);
        unsafeAtomicAdd(&dst[F + threadIdx.x], ls[F + threadIdx.x]);
    }
}

// --- layer-1 MFMA GEMM: C stored in RAW FRAGMENT layout (Tfrag) -------------
// Tfrag[tile][ (ct*4+w)*64 + lane ][4 bf16] -- coalesced uint2/lane, no LDS
// transpose. Consumed by apply1_head with the identical decomposition.
__global__ __launch_bounds__(256) void mfma_gemmb128f(const unsigned short* __restrict__ Ab,
                                                      const unsigned* __restrict__ WT0,
                                                      const unsigned* __restrict__ WT1,
                                                      unsigned short* __restrict__ Tfrag,
                                                      float* __restrict__ sums_base,
                                                      int n) {
    __shared__ float ls[256];
    int BPS = (n + 63) >> 6;
    int slice = blockIdx.x >= BPS;
    int sb = blockIdx.x - slice * BPS;
    const unsigned* WT = slice ? WT1 : WT0;
    int row0 = slice * n + sb * 64;
    int rows = min(64, n - sb * 64);
    for (int i = threadIdx.x; i < 256; i += 256) ls[i] = 0.f;
    int w = threadIdx.x >> 6, lane = threadIdx.x & 63, q = lane >> 4, ln = lane & 15;
    const unsigned* A32 = (const unsigned*)Ab;
    size_t arow = (size_t)(row0 + 16 * w + ln) * 32;
    v8s af0 = *(const v8s*)&A32[arow + q * 4];
    v8s af1 = *(const v8s*)&A32[arow + 16 + q * 4];
    f32x4 acc[8];
#pragma unroll
    for (int ct = 0; ct < 8; ++ct) acc[ct] = {0.f, 0.f, 0.f, 0.f};
#pragma unroll
    for (int ct = 0; ct < 8; ++ct) {
        v8s b0 = *(const v8s*)&WT[(ct * 16 + ln) * 32 + q * 4];
        v8s b1 = *(const v8s*)&WT[(ct * 16 + ln) * 32 + 16 + q * 4];
        acc[ct] = __builtin_amdgcn_mfma_f32_16x16x32_bf16(af0, b0, acc[ct], 0, 0, 0);
        acc[ct] = __builtin_amdgcn_mfma_f32_16x16x32_bf16(af1, b1, acc[ct], 0, 0, 0);
    }
    __syncthreads();  // ls zero-init visible
    unsigned short* tb = Tfrag + (size_t)blockIdx.x * 8192;
#pragma unroll
    for (int ct = 0; ct < 8; ++ct) {
        uint2 o2;
        o2.x = pack2(acc[ct][0], acc[ct][1]);
        o2.y = pack2(acc[ct][2], acc[ct][3]);
        *(uint2*)&tb[((ct * 4 + w) * 64 + lane) * 4] = o2;
        float s1 = 0.f, s2 = 0.f;
        int cc = ct * 16 + ln;
#pragma unroll
        for (int i = 0; i < 4; ++i) {
            int r = 16 * w + q * 4 + i;
            if (r < rows) {
                float v = acc[ct][i];
                s1 += v;
                s2 += v * v;
            }
        }
        s1 += __shfl_xor(s1, 16); s1 += __shfl_xor(s1, 32);
        s2 += __shfl_xor(s2, 16); s2 += __shfl_xor(s2, 32);
        if (q == 0) {
            atomicAdd(&ls[cc], s1);
            atomicAdd(&ls[128 + cc], s2);
        }
    }
    __syncthreads();
    if (threadIdx.x < 128) {
        float* dst = sums_base + (blockIdx.x & 7) * 1024 + slice * 256;
        unsafeAtomicAdd(&dst[threadIdx.x], ls[threadIdx.x]);
        unsafeAtomicAdd(&dst[128 + threadIdx.x], ls[128 + threadIdx.x]);
    }
}

// h1 = san(relu(bn(t0b)) + x); BN finalize fused (from sums); 8 elems/thread.
__global__ __launch_bounds__(256) void apply0_kernel(const unsigned short* __restrict__ t0b,
                                                     const float* __restrict__ x,
                                                     const float* __restrict__ sums_base,
                                                     const float* __restrict__ g,
                                                     const float* __restrict__ be,
                                                     const float* __restrict__ dinv,
                                                     unsigned short* __restrict__ h1b,
                                                     unsigned short* __restrict__ h1sb,
                                                     int n64, int total, int n) {
    __shared__ float sc[256];  // [slice*128 + {f, 64+f}]
    int t = threadIdx.x;
    if (t < 128) {  // fused bnfinal<64>, both slices
        int slice = t >> 6, f = t & 63;
        float s1 = 0.f, s2 = 0.f;
#pragma unroll
        for (int r = 0; r < 8; ++r) {
            const float* src = sums_base + r * 1024 + 512 + slice * 128;
            s1 += src[f];
            s2 += src[64 + f];
        }
        float inv_n = 1.0f / (float)n;
        float mu = s1 * inv_n;
        float var = fmaxf(s2 * inv_n - mu * mu, 0.f);
        float scale = g[f] * rsqrtf(var + 1e-5f);
        sc[slice * 128 + f] = scale;
        sc[slice * 128 + 64 + f] = be[f] - mu * scale;
    }
    __syncthreads();
    int i8 = (blockIdx.x * 256 + t) * 8;
    if (i8 >= total) return;
    int slice = i8 >= n64;
    int f0 = i8 & 63;
    const float* scp = sc + slice * 128;
    uint4 tv = *(const uint4*)&t0b[i8];
    const float* xp = x + (i8 - slice * n64);
    float4 x0 = *(const float4*)xp;
    float4 x1 = *(const float4*)(xp + 4);
    float4 s0 = *(const float4*)&scp[f0];
    float4 s1 = *(const float4*)&scp[f0 + 4];
    float4 g0 = *(const float4*)&scp[64 + f0];
    float4 g1 = *(const float4*)&scp[64 + f0 + 4];
    float d = dinv[i8 >> 6];
    float tvv[8] = {uflo(tv.x), ufhi(tv.x), uflo(tv.y), ufhi(tv.y),
                    uflo(tv.z), ufhi(tv.z), uflo(tv.w), ufhi(tv.w)};
    float sa[8] = {s0.x, s0.y, s0.z, s0.w, s1.x, s1.y, s1.z, s1.w};
    float sh[8] = {g0.x, g0.y, g0.z, g0.w, g1.x, g1.y, g1.z, g1.w};
    float xv[8] = {x0.x, x0.y, x0.z, x0.w, x1.x, x1.y, x1.z, x1.w};
    unsigned po[4], ps[4];
#pragma unroll
    for (int j = 0; j < 4; ++j) {
        float a = sanf(fmaxf(fmaf(tvv[2 * j], sa[2 * j], sh[2 * j]), 0.f) + xv[2 * j]);
        float b = sanf(fmaxf(fmaf(tvv[2 * j + 1], sa[2 * j + 1], sh[2 * j + 1]), 0.f) + xv[2 * j + 1]);
        po[j] = pack2(a, b);
        ps[j] = pack2(a * d, b * d);
    }
    *(uint4*)&h1b[i8] = *(uint4*)po;
    *(uint4*)&h1sb[i8] = *(uint4*)ps;
}

// --- fused apply1 + head, fragment-layout edition ----------------------------
// Per row-tile: BN scales -> per slice {res-GEMM acc; read Tfrag uint2;
// o = san(bn(tf)+acc) on regs; scalar bf16 writes into swizzled cmb LDS} ->
// head fc1-MFMA (A from cmb) + fc2 + softmax. No f32 stage: LDS ~34.8 KB.
__global__ __launch_bounds__(256) void apply1_head(const unsigned short* __restrict__ h1b,
                                                   const unsigned short* __restrict__ Tfrag,
                                                   const unsigned* __restrict__ RT0,
                                                   const unsigned* __restrict__ RT1,
                                                   const unsigned* __restrict__ FT,
                                                   const float* __restrict__ sums_base,
                                                   const float* __restrict__ g,
                                                   const float* __restrict__ be,
                                                   const float* __restrict__ fc1_b,
                                                   const float* __restrict__ w2,
                                                   const float* __restrict__ b2,
                                                   float* __restrict__ out, int n) {
    __shared__ unsigned short cmb[64 * 256];  // 32 KB bf16 comb, XOR-swizzled
    __shared__ float scl[512];                // per-slice scale[128]+shift[128]
    int t = threadIdx.x;
    int BPS = (n + 63) >> 6;
    int row0l = blockIdx.x * 64;
    int rows = min(64, n - row0l);
    {   // fused bnfinal<128>, both slices (roff 0)
        int slice = t >> 7, f = t & 127;
        float s1 = 0.f, s2 = 0.f;
#pragma unroll
        for (int r = 0; r < 8; ++r) {
            const float* src = sums_base + r * 1024 + slice * 256;
            s1 += src[f];
            s2 += src[128 + f];
        }
        float inv_n = 1.0f / (float)n;
        float mu = s1 * inv_n;
        float var = fmaxf(s2 * inv_n - mu * mu, 0.f);
        float scale = g[f] * rsqrtf(var + 1e-5f);
        scl[slice * 256 + f] = scale;
        scl[slice * 256 + 128 + f] = be[f] - mu * scale;
    }
    __syncthreads();
    int w = t >> 6, lane = t & 63, q = lane >> 4, ln = lane & 15;
    int rbase = 16 * w + q * 4;
#pragma unroll
    for (int slice = 0; slice < 2; ++slice) {
        const unsigned* WT = slice ? RT1 : RT0;
        int row0 = slice * n + row0l;
        const unsigned* A32 = (const unsigned*)h1b;
        size_t arow = (size_t)(row0 + 16 * w + ln) * 32;
        v8s af0 = *(const v8s*)&A32[arow + q * 4];
        v8s af1 = *(const v8s*)&A32[arow + 16 + q * 4];
        f32x4 acc[8];
#pragma unroll
        for (int ct = 0; ct < 8; ++ct) acc[ct] = {0.f, 0.f, 0.f, 0.f};
#pragma unroll
        for (int ct = 0; ct < 8; ++ct) {
            v8s b0 = *(const v8s*)&WT[(ct * 16 + ln) * 32 + q * 4];
            v8s b1 = *(const v8s*)&WT[(ct * 16 + ln) * 32 + 16 + q * 4];
            acc[ct] = __builtin_amdgcn_mfma_f32_16x16x32_bf16(af0, b0, acc[ct], 0, 0, 0);
            acc[ct] = __builtin_amdgcn_mfma_f32_16x16x32_bf16(af1, b1, acc[ct], 0, 0, 0);
        }
        const unsigned short* tb = Tfrag + (size_t)(slice * BPS + blockIdx.x) * 8192;
        const float* scb = scl + slice * 256;
#pragma unroll
        for (int ct = 0; ct < 8; ++ct) {
            uint2 tf = *(const uint2*)&tb[((ct * 4 + w) * 64 + lane) * 4];
            int c = ct * 16 + ln;
            float sc_ = scb[c], sh_ = scb[128 + c];
            float o0 = sanf(fmaf(uflo(tf.x), sc_, sh_) + acc[ct][0]);
            float o1 = sanf(fmaf(ufhi(tf.x), sc_, sh_) + acc[ct][1]);
            float o2 = sanf(fmaf(uflo(tf.y), sc_, sh_) + acc[ct][2]);
            float o3 = sanf(fmaf(ufhi(tf.y), sc_, sh_) + acc[ct][3]);
            int gc = slice * 128 + c;
            cmb[(rbase + 0) * 256 + (gc ^ (((rbase + 0) & 7) << 3))] = bf16of(o0);
            cmb[(rbase + 1) * 256 + (gc ^ (((rbase + 1) & 7) << 3))] = bf16of(o1);
            cmb[(rbase + 2) * 256 + (gc ^ (((rbase + 2) & 7) << 3))] = bf16of(o2);
            cmb[(rbase + 3) * 256 + (gc ^ (((rbase + 3) & 7) << 3))] = bf16of(o3);
        }
    }
    __syncthreads();  // cmb complete
    // ---- head: fc1 MFMA (A from LDS cmb) + relu + fc2 + softmax ----
    {
        int rowLocal = 16 * w + ln;
        const unsigned short* cr = cmb + rowLocal * 256;
        int swzR = (rowLocal & 7) << 3;  // u16-index XOR (matches write side)
        f32x4 acc[8];
#pragma unroll
        for (int ct = 0; ct < 8; ++ct) acc[ct] = {0.f, 0.f, 0.f, 0.f};
#pragma unroll
        for (int kt = 0; kt < 4; ++kt) {
            v8s af0 = *(const v8s*)&cr[(kt * 64 + q * 8) ^ swzR];
            v8s af1 = *(const v8s*)&cr[(kt * 64 + 32 + q * 8) ^ swzR];
#pragma unroll
            for (int ct = 0; ct < 8; ++ct) {
                v8s b0 = *(const v8s*)&FT[(ct * 16 + ln) * 128 + kt * 32 + q * 4];
                v8s b1 = *(const v8s*)&FT[(ct * 16 + ln) * 128 + kt * 32 + 16 + q * 4];
                acc[ct] = __builtin_amdgcn_mfma_f32_16x16x32_bf16(af0, b0, acc[ct], 0, 0, 0);
                acc[ct] = __builtin_amdgcn_mfma_f32_16x16x32_bf16(af1, b1, acc[ct], 0, 0, 0);
            }
        }
        float p0[4] = {0.f, 0.f, 0.f, 0.f}, p1[4] = {0.f, 0.f, 0.f, 0.f};
#pragma unroll
        for (int ct = 0; ct < 8; ++ct) {
            int c = ct * 16 + ln;
            float bi = fc1_b[c];
            float w20 = w2[c * 2], w21 = w2[c * 2 + 1];
#pragma unroll
            for (int i = 0; i < 4; ++i) {
                float h = fmaxf(acc[ct][i] + bi, 0.f);
                p0[i] = fmaf(h, w20, p0[i]);
                p1[i] = fmaf(h, w21, p1[i]);
            }
        }
#pragma unroll
        for (int i = 0; i < 4; ++i) {
#pragma unroll
            for (int msk = 1; msk < 16; msk <<= 1) {
                p0[i] += __shfl_xor(p0[i], msk);
                p1[i] += __shfl_xor(p1[i], msk);
            }
        }
        if (ln == 0) {
            float bb0 = b2[0], bb1 = b2[1];
#pragma unroll
            for (int i = 0; i < 4; ++i) {
                int r = 16 * w + q * 4 + i;
                if (r >= rows) continue;
                int R = row0l + r;
                float l0 = p0[i] + bb0, l1 = p1[i] + bb1;
                float mx = fmaxf(l0, l1);
                float e0 = expf(l0 - mx), e1 = expf(l1 - mx);
                float inv = 1.0f / (e0 + e1);
                out[(size_t)R * 2] = l0;
                out[(size_t)R * 2 + 1] = l1;
                out[(size_t)2 * n + R * 2] = e0 * inv;
                out[(size_t)2 * n + R * 2 + 1] = e1 * inv;
            }
        }
    }
}

static inline int cdiv(int a, int b) { return (a + b - 1) / b; }

extern "C" void kernel_launch(void* const* d_in, const int* in_sizes, int n_in,
                              void* d_out, int out_size, void* d_ws, size_t ws_size,
                              hipStream_t stream) {
    const float* x       = (const float*)d_in[0];
    const int*   ei0     = (const int*)d_in[1];
    const int*   ei1     = (const int*)d_in[2];
    const float* w0_s0   = (const float*)d_in[3];
    const float* w1_s0   = (const float*)d_in[5];
    const float* res1_s0 = (const float*)d_in[7];
    const float* w0_s1   = (const float*)d_in[8];
    const float* w1_s1   = (const float*)d_in[10];
    const float* res1_s1 = (const float*)d_in[12];
    const float* bn_g0   = (const float*)d_in[13];
    const float* bn_b0   = (const float*)d_in[14];
    const float* bn_g1   = (const float*)d_in[15];
    const float* bn_b1   = (const float*)d_in[16];
    const float* fc1_w   = (const float*)d_in[17];
    const float* fc1_b   = (const float*)d_in[18];
    const float* fc2_w   = (const float*)d_in[19];
    const float* fc2_b   = (const float*)d_in[20];
    float* out = (float*)d_out;

    int n = in_sizes[0] / 64;   // 50000
    int E = in_sizes[1] / 2;    // 1600000
    int n2 = 2 * n, E2 = 2 * E;
    int n64 = n * 64;
    int NB = cdiv(n2, 256);     // 391 buckets (256 cols each)
    int BPS = cdiv(n, 64);      // 782 row-tiles per slice
    int GB = 8 * cdiv(cdiv(n, 32), 4);  // gather grid: XCD-affine, 32 nodes/block

    // X1 sized for Tfrag: 2*BPS tiles x 8192 u16 = 2*BPS*4096 f32
    float* X1 = (float*)d_ws;
    float* S  = X1 + (size_t)2 * BPS * 4096;        // h1sb region
    unsigned short* Gb   = (unsigned short*)(S + (size_t)n2 * 64);
    unsigned short* h1b  = Gb + (size_t)n2 * 64;
    unsigned short* comb = h1b + (size_t)n2 * 64;   // binned overlay region only
    unsigned short* xsb  = comb + (size_t)n * 256;  // n*128 u16
    float* dinv = (float*)(xsb + (size_t)n * 128);
    float* sums = dinv + n2;                        // [8][1024] replicas
    float* scsh = sums + 8192;                      // (layout spacer)
    unsigned* wpk = (unsigned*)(scsh + 512);        // [36864]
    unsigned short* csr = (unsigned short*)(wpk + 36864);  // [E2] u16
    int* rowptr = (int*)(csr + (size_t)E2);
    int* bcnt   = rowptr + (n2 + 1);                // [512]
    unsigned short* t0b = (unsigned short*)X1;      // layer-0 row-major C
    unsigned short* Tfrag = (unsigned short*)X1;    // layer-1 fragment C
    unsigned* binned = (unsigned*)comb;
    unsigned short* h1sb = (unsigned short*)S;
    unsigned* w0T0 = wpk + 0,    *w0T1 = wpk + 2048;
    unsigned* w1T0 = wpk + 4096, *w1T1 = wpk + 8192;
    unsigned* rT0  = wpk + 12288,*rT1  = wpk + 16384;
    unsigned* fT   = wpk + 20480;

    // --- prep (weight pack + zero bcnt/sums) + CSR build (+prescale tail) ---
    prep_kernel<<<144, 256, 0, stream>>>(w0_s0, w0_s1, w1_s0, w1_s1,
                                         res1_s0, res1_s1, fc1_w, wpk, bcnt, sums);
    kC_bin<<<cdiv(E2, 8192), 512, 0, stream>>>(ei0, ei1, bcnt, binned, E, n);
    kD_build<<<NB, 512, 0, stream>>>(binned, bcnt, x, rowptr, dinv, csr, xsb, n2, NB);

    // --- layer 0 ---
    gatherbf_kernel<<<GB, 256, 0, stream>>>(rowptr, csr, xsb, dinv, Gb, n);
    mfma_gemmb64<<<2 * BPS, 256, 0, stream>>>(Gb, w0T0, w0T1, t0b, sums, 512, n);
    apply0_kernel<<<cdiv(2 * n64, 2048), 256, 0, stream>>>(t0b, x, sums, bn_g0, bn_b0,
                                                           dinv, h1b, h1sb, n64, 2 * n64, n);

    // --- layer 1 (fragment-layout C) ---
    gatherbf_kernel<<<GB, 256, 0, stream>>>(rowptr, csr, h1sb, dinv, Gb, n);
    mfma_gemmb128f<<<2 * BPS, 256, 0, stream>>>(Gb, w1T0, w1T1, Tfrag, sums, n);

    // --- fused apply1 + head (comb in LDS, no f32 stage) ---
    apply1_head<<<BPS, 256, 0, stream>>>(h1b, Tfrag, rT0, rT1, fT, sums, bn_g1, bn_b1,
                                         fc1_b, fc2_w, fc2_b, out, n);
}